// Round 8
// baseline (1058.654 us; speedup 1.0000x reference)
//
#include <hip/hip_runtime.h>
#include <hip/hip_bf16.h>

#define NTOK 8192
#define SCC  16
#define CD   128
#define WD   512
#define OD   1024
#define ED   640   // WD + CD
#define TW   8     // tokens per scan workgroup

typedef __attribute__((ext_vector_type(8))) short short8;
typedef __attribute__((ext_vector_type(4))) float f32x4;

__device__ __forceinline__ unsigned short f2bf(float f) {
    union { float f; unsigned u; } v; v.f = f;
    unsigned r = v.u + 0x7FFF + ((v.u >> 16) & 1);   // RNE
    return (unsigned short)(r >> 16);
}

// ---------------------------------------------------------------------------
// Deterministic stable counting sort of tokens by length (16 bins).
// ws ints: [0..15]=hist [16..31]=base [32..47]=unused [48..48+NTOK)=order
// ---------------------------------------------------------------------------
__global__ void sort_zero(int* s) { if (threadIdx.x < 48) s[threadIdx.x] = 0; }

__global__ void sort_hist(const int* __restrict__ lengths, int* __restrict__ s) {
    const int i = blockIdx.x * 256 + threadIdx.x;
    if (i < NTOK) atomicAdd(&s[lengths[i] - 1], 1);
}

__global__ void sort_prefix(int* s) {
    if (threadIdx.x == 0) {
        int acc = 0;
        for (int b = 0; b < 16; ++b) { s[16 + b] = acc; acc += s[b]; }
    }
}

// one block per bin; ballot-based stable rank — bit-deterministic every call
__global__ __launch_bounds__(256) void sort_scatter_det(
    const int* __restrict__ lengths, int* __restrict__ s)
{
    __shared__ int wsum[4];
    __shared__ int running;
    const int b   = blockIdx.x;
    const int tid = threadIdx.x;
    if (tid == 0) running = s[16 + b];
    __syncthreads();
    for (int c0 = 0; c0 < NTOK; c0 += 256) {
        const int i = c0 + tid;
        const bool f = (lengths[i] - 1 == b);
        const unsigned long long m = __ballot(f);
        const int wv = tid >> 6;
        if ((tid & 63) == 0) wsum[wv] = __popcll(m);
        __syncthreads();
        int excl = 0;
#pragma unroll
        for (int k = 0; k < 4; ++k) if (k < wv) excl += wsum[k];
        const int lanerank = __popcll(m & ((1ull << (tid & 63)) - 1ull));
        if (f) s[48 + running + excl + lanerank] = i;
        const int tot = wsum[0] + wsum[1] + wsum[2] + wsum[3];
        __syncthreads();
        if (tid == 0) running += tot;
        __syncthreads();
    }
}

// ---------------------------------------------------------------------------
// Kernel 0: pack Wg(384x256)+Wp(128x256) fp32 -> bf16 B-fragment layout.
// lane l holds B[k=(l>>4)*8+e][n=l&15], e=0..7. n = c*128 + w*16 + (l&15).
// index: ((w*4+c)*8+kf)*64 + lane, entry = uint4 (8 bf16 along k).
// ---------------------------------------------------------------------------
__global__ __launch_bounds__(256) void pack_weights(
    const float* __restrict__ Wg, const float* __restrict__ Wp,
    uint4* __restrict__ packed)
{
    const int gid  = blockIdx.x * 256 + threadIdx.x;  // 0..16383
    const int lane = gid & 63;
    const int kf   = (gid >> 6) & 7;
    const int c    = (gid >> 9) & 3;
    const int w    = (gid >> 11) & 7;
    const int n    = c * 128 + w * 16 + (lane & 15);
    const int k0   = kf * 32 + (lane >> 4) * 8;
    const float* src = (n < 384) ? (Wg + n * 256 + k0) : (Wp + (n - 384) * 256 + k0);
    uint4 o;
    o.x = f2bf(src[0]) | ((unsigned)f2bf(src[1]) << 16);
    o.y = f2bf(src[2]) | ((unsigned)f2bf(src[3]) << 16);
    o.z = f2bf(src[4]) | ((unsigned)f2bf(src[5]) << 16);
    o.w = f2bf(src[6]) | ((unsigned)f2bf(src[7]) << 16);
    packed[gid] = o;
}

// ---------------------------------------------------------------------------
// Kernel 1: MFMA gated pyramid scan, TW=8 sorted tokens/WG, 8 waves.
// Weights are NOT register-resident (R5-R7: arch-VGPR class caps at 128 and
// wreg[4][8]=128 spills; 3 rounds confirmed). B-fragments stream from L2
// inside the kf loop; TW=8 amortizes each load over up to 8 M-frags.
// acc[8][4] = 128 regs -> AGPR class; arch class (b+a+addr) ~80 -> both <=128.
// X row r = p*8 + t, static across steps; combine writes X directly.
// LDS 128 KB -> 1 WG/CU, 2 waves/EU.
// ---------------------------------------------------------------------------
__global__ __launch_bounds__(512, 2) void scan_mfma(
    const int*   __restrict__ char_ids,
    const int*   __restrict__ char_lengths,
    const float* __restrict__ char_table,
    const float* __restrict__ bg, const float* __restrict__ bp,
    const uint4* __restrict__ Wpacked,
    const int*   __restrict__ order,
    unsigned short* __restrict__ char_repr)
{
    __shared__ __align__(16) float S[TW * SCC * CD];          // 64 KB fp32 state
    __shared__ __align__(16) unsigned short X[128 * 256];     // 64 KB bf16, swizzled
    __shared__ int toksh[TW];
    __shared__ int Lsh[TW];

    const int tid  = threadIdx.x;
    const int lane = tid & 63;
    const int w    = tid >> 6;         // wave 0..7
    const int col  = lane & 15;
    const int q    = lane >> 4;        // 0..3

    if (tid < TW) {
        const int tok = order[blockIdx.x * TW + tid];
        toksh[tid] = tok;
        Lsh[tid]   = char_lengths[tok];
    }

    const int dj = w * 16 + col;
    float biasv[4];
    biasv[0] = bg[dj];
    biasv[1] = bg[128 + dj];
    biasv[2] = bg[256 + dj];
    biasv[3] = bp[dj];

    __syncthreads();

    // init state: S[t][c][d] = char_table[ids[tok[t]][c]][d]
    for (int i = tid; i < TW * SCC * (CD / 4); i += 512) {
        const int t   = i >> 9;
        const int rem = i & 511;
        const int c   = rem >> 5;
        const int d4  = rem & 31;
        const int id  = char_ids[toksh[t] * SCC + c];
        reinterpret_cast<float4*>(S)[i] =
            reinterpret_cast<const float4*>(char_table + id * CD)[d4];
    }

    int L[TW];
#pragma unroll
    for (int t = 0; t < TW; ++t) L[t] = Lsh[t];
    int maxL = L[0];
#pragma unroll
    for (int t = 1; t < TW; ++t) maxL = max(maxL, L[t]);

    __syncthreads();

    // init X once: row r=p*8+t = [S[t][p] | S[t][p+1]] bf16,
    // p=15 rows zero-filled (never active, keeps MFMA inputs finite).
    for (int i = tid; i < 128 * 128; i += 512) {
        const int r  = i >> 7;
        const int ku = i & 127;
        const int p  = r >> 3;
        const int t  = r & 7;
        unsigned u = 0u;
        if (p < 15) {
            const float2 v = reinterpret_cast<const float2*>(S + t * 2048 + p * 128)[ku];
            u = f2bf(v.x) | ((unsigned)f2bf(v.y) << 16);
        }
        int baddr = (r << 9) + (ku << 2);
        baddr ^= (r & 7) << 4;
        *reinterpret_cast<unsigned*>(reinterpret_cast<char*>(X) + baddr) = u;
    }
    __syncthreads();

    for (int len = 1; len < maxL; ++len) {
        const int Amax   = maxL - len;                 // max active p-rows
        const int mfrags = (8 * Amax + 15) >> 4;       // <= 8

        f32x4 acc[8][4];   // [m-frag][chunk] -> 128 regs (AGPR class)
#pragma unroll
        for (int m = 0; m < 8; ++m)
#pragma unroll
            for (int c = 0; c < 4; ++c) acc[m][c] = (f32x4){0.f, 0.f, 0.f, 0.f};

        // ---- MFMA phase: A from LDS X, B streamed from L2 ----
#pragma unroll
        for (int kf = 0; kf < 8; ++kf) {
            short8 b[4];
#pragma unroll
            for (int c = 0; c < 4; ++c) {
                union { uint4 u; short8 s; } cv;
                cv.u = Wpacked[((w * 4 + c) * 8 + kf) * 64 + lane];
                b[c] = cv.s;
            }
#pragma unroll
            for (int m = 0; m < 8; ++m) {
                if (m < mfrags) {
                    const int row = m * 16 + col;
                    int baddr = (row << 9) + (kf << 6) + (q << 4);
                    baddr ^= (row & 7) << 4;
                    const short8 a = *reinterpret_cast<const short8*>(
                        reinterpret_cast<const char*>(X) + baddr);
#pragma unroll
                    for (int c = 0; c < 4; ++c)
                        acc[m][c] = __builtin_amdgcn_mfma_f32_16x16x32_bf16(
                            a, b[c], acc[m][c], 0, 0, 0);
                }
            }
        }

        // ---- combine: lane-local softmax + convex mix ----
        // output row r = m*16 + q*4 + i -> t = r&7, p = r>>3 (static)
#pragma unroll
        for (int m = 0; m < 8; ++m) {
            if (m < mfrags) {
#pragma unroll
                for (int i = 0; i < 4; ++i) {
                    const int r = m * 16 + q * 4 + i;
                    const int t = r & 7, p = r >> 3;
                    const float g0 = acc[m][0][i] + biasv[0];
                    const float g1 = acc[m][1][i] + biasv[1];
                    const float g2 = acc[m][2][i] + biasv[2];
                    const float z  = acc[m][3][i] + biasv[3];
                    const float mx = fmaxf(fmaxf(g0, g1), g2);
                    const float e0 = __expf(g0 - mx);
                    const float e1 = __expf(g1 - mx);
                    const float e2 = __expf(g2 - mx);
                    const float left  = S[t * 2048 + p * 128 + dj];
                    const float right = S[t * 2048 + (p + 1) * 128 + dj];
                    const float inv = __builtin_amdgcn_rcpf(e0 + e1 + e2);
                    acc[m][0][i] = (e0 * left + e1 * right + e2 * z) * inv;
                }
            }
        }
        __syncthreads();   // all X-reads (MFMA) and S-reads (combine) done

        // ---- write phase: masked fp32 S + bf16 X (left @ r, right @ r-8) ----
#pragma unroll
        for (int m = 0; m < 8; ++m) {
            if (m < mfrags) {
#pragma unroll
                for (int i = 0; i < 4; ++i) {
                    const int r = m * 16 + q * 4 + i;
                    const int t = r & 7, p = r >> 3;
                    const float val = acc[m][0][i];
                    if (p < L[t] - len) S[t * 2048 + p * 128 + dj] = val;
                    const unsigned short bv = f2bf(val);
                    int bl = (r << 9) + (dj << 1);
                    bl ^= (r & 7) << 4;
                    *reinterpret_cast<unsigned short*>(
                        reinterpret_cast<char*>(X) + bl) = bv;
                    if (p >= 1) {
                        const int rr = r - 8;                  // row (p-1)*8+t
                        int br = (rr << 9) + 256 + (dj << 1);
                        br ^= (rr & 7) << 4;
                        *reinterpret_cast<unsigned short*>(
                            reinterpret_cast<char*>(X) + br) = bv;
                    }
                }
            }
        }
        __syncthreads();
    }

    // char representation = S[t][0][:], stored bf16
    for (int i = tid; i < TW * CD; i += 512) {
        const int t = i >> 7, d = i & 127;
        char_repr[toksh[t] * CD + d] = f2bf(S[t * 2048 + d]);
    }
}

// ---------------------------------------------------------------------------
// Kernel 2: out[t][j] = b_out[j] + emb[t] . W_out[j]
// ---------------------------------------------------------------------------
#define TPB2 16

__global__ __launch_bounds__(256) void out_gemm(
    const int*   __restrict__ word_inputs,
    const float* __restrict__ word_table,
    const unsigned short* __restrict__ char_repr,   // bf16 bits
    const float* __restrict__ W_out,
    const float* __restrict__ b_out,
    float*       __restrict__ out)
{
    __shared__ __align__(16) float E[TPB2 * ED];  // 40 KB

    const int tg  = blockIdx.x * TPB2;
    const int tid = threadIdx.x;

    for (int i = tid; i < TPB2 * WD; i += 256) {
        const int tl = i >> 9, k = i & 511;
        E[tl * ED + k] = word_table[(size_t)word_inputs[tg + tl] * WD + k];
    }
    for (int i = tid; i < TPB2 * CD; i += 256) {
        const int tl = i >> 7, k = i & 127;
        union { unsigned u; float f; } qq;
        qq.u = ((unsigned)char_repr[(tg + tl) * CD + k]) << 16;
        E[tl * ED + WD + k] = qq.f;
    }
    __syncthreads();

    const int j0 = tid * 4;
    float acc[TPB2][4];
#pragma unroll
    for (int tl = 0; tl < TPB2; ++tl)
#pragma unroll
        for (int jj = 0; jj < 4; ++jj) acc[tl][jj] = 0.f;

#pragma unroll 2
    for (int kc = 0; kc < ED / 4; ++kc) {
        const int k = kc * 4;
        float4 wr[4];
#pragma unroll
        for (int jj = 0; jj < 4; ++jj)
            wr[jj] = *reinterpret_cast<const float4*>(W_out + (size_t)(j0 + jj) * ED + k);
#pragma unroll
        for (int tl = 0; tl < TPB2; ++tl) {
            const float4 e = *reinterpret_cast<const float4*>(E + tl * ED + k);
#pragma unroll
            for (int jj = 0; jj < 4; ++jj) {
                acc[tl][jj] = fmaf(wr[jj].x, e.x, acc[tl][jj]);
                acc[tl][jj] = fmaf(wr[jj].y, e.y, acc[tl][jj]);
                acc[tl][jj] = fmaf(wr[jj].z, e.z, acc[tl][jj]);
                acc[tl][jj] = fmaf(wr[jj].w, e.w, acc[tl][jj]);
            }
        }
    }

    const float4 bb = *reinterpret_cast<const float4*>(b_out + j0);
#pragma unroll
    for (int tl = 0; tl < TPB2; ++tl) {
        float4 r;
        r.x = acc[tl][0] + bb.x;
        r.y = acc[tl][1] + bb.y;
        r.z = acc[tl][2] + bb.z;
        r.w = acc[tl][3] + bb.w;
        *reinterpret_cast<float4*>(out + (size_t)(tg + tl) * OD + j0) = r;
    }
}

// ---------------------------------------------------------------------------

extern "C" void kernel_launch(void* const* d_in, const int* in_sizes, int n_in,
                              void* d_out, int out_size, void* d_ws, size_t ws_size,
                              hipStream_t stream)
{
    const int*   word_inputs  = (const int*)  d_in[0];
    const int*   char_ids     = (const int*)  d_in[1];
    const int*   char_lengths = (const int*)  d_in[2];
    const float* word_table   = (const float*)d_in[3];
    const float* char_table   = (const float*)d_in[4];
    const float* Wg           = (const float*)d_in[5];
    const float* bg           = (const float*)d_in[6];
    const float* Wp           = (const float*)d_in[7];
    const float* bp           = (const float*)d_in[8];
    const float* W_out        = (const float*)d_in[9];
    const float* b_out        = (const float*)d_in[10];

    float* out = (float*)d_out;
    unsigned short* char_repr = (unsigned short*)d_ws;              // 2 MB bf16
    uint4* Wpacked = (uint4*)((char*)d_ws + 2 * 1024 * 1024);       // 256 KB
    int*   sortbuf = (int*)((char*)d_ws + 2 * 1024 * 1024 + 256 * 1024);
    const int* order = sortbuf + 48;

    pack_weights<<<64, 256, 0, stream>>>(Wg, Wp, Wpacked);
    sort_zero<<<1, 64, 0, stream>>>(sortbuf);
    sort_hist<<<NTOK / 256, 256, 0, stream>>>(char_lengths, sortbuf);
    sort_prefix<<<1, 64, 0, stream>>>(sortbuf);
    sort_scatter_det<<<16, 256, 0, stream>>>(char_lengths, sortbuf);

    scan_mfma<<<NTOK / TW, 512, 0, stream>>>(char_ids, char_lengths, char_table,
                                             bg, bp, Wpacked, order, char_repr);
    out_gemm<<<NTOK / TPB2, 256, 0, stream>>>(word_inputs, word_table, char_repr,
                                              W_out, b_out, out);
}

// Round 9
// 513.357 us; speedup vs baseline: 2.0622x; 2.0622x over previous
//
#include <hip/hip_runtime.h>
#include <hip/hip_bf16.h>

#define NTOK 8192
#define SCC  16
#define CD   128
#define WD   512
#define OD   1024
#define ED   640   // WD + CD
#define TW   4     // tokens per scan workgroup

typedef __attribute__((ext_vector_type(8))) short short8;
typedef __attribute__((ext_vector_type(4))) float f32x4;

__device__ __forceinline__ unsigned short f2bf(float f) {
    union { float f; unsigned u; } v; v.f = f;
    unsigned r = v.u + 0x7FFF + ((v.u >> 16) & 1);   // RNE
    return (unsigned short)(r >> 16);
}

// ---------------------------------------------------------------------------
// Deterministic stable counting sort of tokens by length (16 bins).
// ws ints: [0..15]=hist [16..31]=base [32..47]=unused [48..48+NTOK)=order
// ---------------------------------------------------------------------------
__global__ void sort_zero(int* s) { if (threadIdx.x < 48) s[threadIdx.x] = 0; }

__global__ void sort_hist(const int* __restrict__ lengths, int* __restrict__ s) {
    const int i = blockIdx.x * 256 + threadIdx.x;
    if (i < NTOK) atomicAdd(&s[lengths[i] - 1], 1);
}

__global__ void sort_prefix(int* s) {
    if (threadIdx.x == 0) {
        int acc = 0;
        for (int b = 0; b < 16; ++b) { s[16 + b] = acc; acc += s[b]; }
    }
}

// one block per bin; ballot-based stable rank — bit-deterministic every call
__global__ __launch_bounds__(256) void sort_scatter_det(
    const int* __restrict__ lengths, int* __restrict__ s)
{
    __shared__ int wsum[4];
    __shared__ int running;
    const int b   = blockIdx.x;
    const int tid = threadIdx.x;
    if (tid == 0) running = s[16 + b];
    __syncthreads();
    for (int c0 = 0; c0 < NTOK; c0 += 256) {
        const int i = c0 + tid;
        const bool f = (lengths[i] - 1 == b);
        const unsigned long long m = __ballot(f);
        const int wv = tid >> 6;
        if ((tid & 63) == 0) wsum[wv] = __popcll(m);
        __syncthreads();
        int excl = 0;
#pragma unroll
        for (int k = 0; k < 4; ++k) if (k < wv) excl += wsum[k];
        const int lanerank = __popcll(m & ((1ull << (tid & 63)) - 1ull));
        if (f) s[48 + running + excl + lanerank] = i;
        const int tot = wsum[0] + wsum[1] + wsum[2] + wsum[3];
        __syncthreads();
        if (tid == 0) running += tot;
        __syncthreads();
    }
}

// ---------------------------------------------------------------------------
// Kernel 0: pack Wg(384x256)+Wp(128x256) fp32 -> bf16 B-fragment layout.
// lane l holds B[k=(l>>4)*8+e][n=l&15], e=0..7. n = c*128 + w*16 + (l&15).
// index: ((w*4+c)*8+kf)*64 + lane, entry = uint4 (8 bf16 along k).
// ---------------------------------------------------------------------------
__global__ __launch_bounds__(256) void pack_weights(
    const float* __restrict__ Wg, const float* __restrict__ Wp,
    uint4* __restrict__ packed)
{
    const int gid  = blockIdx.x * 256 + threadIdx.x;  // 0..16383
    const int lane = gid & 63;
    const int kf   = (gid >> 6) & 7;
    const int c    = (gid >> 9) & 3;
    const int w    = (gid >> 11) & 7;
    const int n    = c * 128 + w * 16 + (lane & 15);
    const int k0   = kf * 32 + (lane >> 4) * 8;
    const float* src = (n < 384) ? (Wg + n * 256 + k0) : (Wp + (n - 384) * 256 + k0);
    uint4 o;
    o.x = f2bf(src[0]) | ((unsigned)f2bf(src[1]) << 16);
    o.y = f2bf(src[2]) | ((unsigned)f2bf(src[3]) << 16);
    o.z = f2bf(src[4]) | ((unsigned)f2bf(src[5]) << 16);
    o.w = f2bf(src[6]) | ((unsigned)f2bf(src[7]) << 16);
    packed[gid] = o;
}

// ---------------------------------------------------------------------------
// Kernel 1: MFMA gated pyramid scan. TW=4 sorted tokens/WG, 8 waves.
// Register-budget law (R5-R8, 4 rounds of evidence): ~128 arch VGPRs and
// ~128 acc VGPRs per wave, hard. So: acc[4][4]=64 (acc class), B-fragments
// streamed from L2 per kf (b[4]=16 arch live), NO register-resident weights.
// Static X layout r = p*4 + t (no per-step X-rebuild; combine writes X
// directly: left @ row p, right @ row p-1). 64.5 KB LDS -> 2 WGs/CU.
// ---------------------------------------------------------------------------
__global__ __launch_bounds__(512, 2) void scan_mfma(
    const int*   __restrict__ char_ids,
    const int*   __restrict__ char_lengths,
    const float* __restrict__ char_table,
    const float* __restrict__ bg, const float* __restrict__ bp,
    const uint4* __restrict__ Wpacked,
    const int*   __restrict__ order,
    unsigned short* __restrict__ char_repr)
{
    __shared__ __align__(16) float S[TW * SCC * CD];          // 32 KB fp32 state
    __shared__ __align__(16) unsigned short X[64 * 256];      // 32 KB bf16, swizzled
    __shared__ int toksh[TW];
    __shared__ int Lsh[TW];

    const int tid  = threadIdx.x;
    const int lane = tid & 63;
    const int w    = tid >> 6;         // wave 0..7
    const int col  = lane & 15;
    const int q    = lane >> 4;        // 0..3

    if (tid < TW) {
        const int tok = order[blockIdx.x * TW + tid];
        toksh[tid] = tok;
        Lsh[tid]   = char_lengths[tok];
    }

    const int dj = w * 16 + col;
    float biasv[4];
    biasv[0] = bg[dj];
    biasv[1] = bg[128 + dj];
    biasv[2] = bg[256 + dj];
    biasv[3] = bp[dj];

    __syncthreads();

    // init state: S[t][c][d] = char_table[ids[tok[t]][c]][d]
    for (int i = tid; i < TW * SCC * (CD / 4); i += 512) {
        const int t   = i >> 9;
        const int rem = i & 511;
        const int c   = rem >> 5;
        const int d4  = rem & 31;
        const int id  = char_ids[toksh[t] * SCC + c];
        reinterpret_cast<float4*>(S)[i] =
            reinterpret_cast<const float4*>(char_table + id * CD)[d4];
    }

    int L[TW];
#pragma unroll
    for (int t = 0; t < TW; ++t) L[t] = Lsh[t];
    const int maxL = max(max(L[0], L[1]), max(L[2], L[3]));

    __syncthreads();

    // init X once: row r=p*4+t = [S[t][p] | S[t][p+1]] bf16,
    // p=15 rows zero-filled (never active, keeps MFMA inputs finite).
    for (int i = tid; i < 64 * 128; i += 512) {
        const int r  = i >> 7;
        const int ku = i & 127;
        const int p  = r >> 2;
        const int t  = r & 3;
        unsigned u = 0u;
        if (p < 15) {
            const float2 v = reinterpret_cast<const float2*>(S + t * 2048 + p * 128)[ku];
            u = f2bf(v.x) | ((unsigned)f2bf(v.y) << 16);
        }
        int baddr = (r << 9) + (ku << 2);
        baddr ^= (r & 7) << 4;
        *reinterpret_cast<unsigned*>(reinterpret_cast<char*>(X) + baddr) = u;
    }
    __syncthreads();

    for (int len = 1; len < maxL; ++len) {
        const int Amax   = maxL - len;
        const int mfrags = (4 * Amax + 15) >> 4;       // <= 4

        f32x4 acc[4][4];   // [m-frag][chunk] -> 64 acc regs
#pragma unroll
        for (int m = 0; m < 4; ++m)
#pragma unroll
            for (int c = 0; c < 4; ++c) acc[m][c] = (f32x4){0.f, 0.f, 0.f, 0.f};

        // ---- MFMA phase: A from LDS X, B streamed from L2 ----
#pragma unroll
        for (int kf = 0; kf < 8; ++kf) {
            short8 b[4];
#pragma unroll
            for (int c = 0; c < 4; ++c) {
                union { uint4 u; short8 s; } cv;
                cv.u = Wpacked[((w * 4 + c) * 8 + kf) * 64 + lane];
                b[c] = cv.s;
            }
#pragma unroll
            for (int m = 0; m < 4; ++m) {
                if (m < mfrags) {
                    const int row = m * 16 + col;
                    int baddr = (row << 9) + (kf << 6) + (q << 4);
                    baddr ^= (row & 7) << 4;
                    const short8 a = *reinterpret_cast<const short8*>(
                        reinterpret_cast<const char*>(X) + baddr);
#pragma unroll
                    for (int c = 0; c < 4; ++c)
                        acc[m][c] = __builtin_amdgcn_mfma_f32_16x16x32_bf16(
                            a, b[c], acc[m][c], 0, 0, 0);
                }
            }
        }

        // ---- combine: lane-local softmax + convex mix. t = i, p = m*4+q ----
#pragma unroll
        for (int m = 0; m < 4; ++m) {
            if (m < mfrags) {
                const int p = m * 4 + q;
#pragma unroll
                for (int i = 0; i < 4; ++i) {
                    const float g0 = acc[m][0][i] + biasv[0];
                    const float g1 = acc[m][1][i] + biasv[1];
                    const float g2 = acc[m][2][i] + biasv[2];
                    const float z  = acc[m][3][i] + biasv[3];
                    const float mx = fmaxf(fmaxf(g0, g1), g2);
                    const float e0 = __expf(g0 - mx);
                    const float e1 = __expf(g1 - mx);
                    const float e2 = __expf(g2 - mx);
                    const float left  = S[i * 2048 + p * 128 + dj];
                    const float right = S[i * 2048 + (p + 1) * 128 + dj];
                    const float inv = __builtin_amdgcn_rcpf(e0 + e1 + e2);
                    acc[m][0][i] = (e0 * left + e1 * right + e2 * z) * inv;
                }
            }
        }
        __syncthreads();   // all X-reads (MFMA) and S-reads (combine) done

        // ---- write phase: masked fp32 S + bf16 X (left @ p, right @ p-1) ----
#pragma unroll
        for (int m = 0; m < 4; ++m) {
            if (m < mfrags) {
                const int p = m * 4 + q;
#pragma unroll
                for (int i = 0; i < 4; ++i) {
                    const float val = acc[m][0][i];
                    if (p < L[i] - len) S[i * 2048 + p * 128 + dj] = val;
                    const unsigned short bv = f2bf(val);
                    const int rl = m * 16 + q * 4 + i;          // row p*4+i
                    int bl = (rl << 9) + (dj << 1);
                    bl ^= (rl & 7) << 4;
                    *reinterpret_cast<unsigned short*>(
                        reinterpret_cast<char*>(X) + bl) = bv;
                    if (p >= 1) {
                        const int rr = rl - 4;                  // row (p-1)*4+i
                        int br = (rr << 9) + 256 + (dj << 1);
                        br ^= (rr & 7) << 4;
                        *reinterpret_cast<unsigned short*>(
                            reinterpret_cast<char*>(X) + br) = bv;
                    }
                }
            }
        }
        __syncthreads();
    }

    // char representation = S[t][0][:], stored bf16
    for (int i = tid; i < TW * CD; i += 512) {
        const int t = i >> 7, d = i & 127;
        char_repr[toksh[t] * CD + d] = f2bf(S[t * 2048 + d]);
    }
}

// ---------------------------------------------------------------------------
// Kernel 2: out[t][j] = b_out[j] + emb[t] . W_out[j]
// ---------------------------------------------------------------------------
#define TPB2 16

__global__ __launch_bounds__(256) void out_gemm(
    const int*   __restrict__ word_inputs,
    const float* __restrict__ word_table,
    const unsigned short* __restrict__ char_repr,   // bf16 bits
    const float* __restrict__ W_out,
    const float* __restrict__ b_out,
    float*       __restrict__ out)
{
    __shared__ __align__(16) float E[TPB2 * ED];  // 40 KB

    const int tg  = blockIdx.x * TPB2;
    const int tid = threadIdx.x;

    for (int i = tid; i < TPB2 * WD; i += 256) {
        const int tl = i >> 9, k = i & 511;
        E[tl * ED + k] = word_table[(size_t)word_inputs[tg + tl] * WD + k];
    }
    for (int i = tid; i < TPB2 * CD; i += 256) {
        const int tl = i >> 7, k = i & 127;
        union { unsigned u; float f; } qq;
        qq.u = ((unsigned)char_repr[(tg + tl) * CD + k]) << 16;
        E[tl * ED + WD + k] = qq.f;
    }
    __syncthreads();

    const int j0 = tid * 4;
    float acc[TPB2][4];
#pragma unroll
    for (int tl = 0; tl < TPB2; ++tl)
#pragma unroll
        for (int jj = 0; jj < 4; ++jj) acc[tl][jj] = 0.f;

#pragma unroll 2
    for (int kc = 0; kc < ED / 4; ++kc) {
        const int k = kc * 4;
        float4 wr[4];
#pragma unroll
        for (int jj = 0; jj < 4; ++jj)
            wr[jj] = *reinterpret_cast<const float4*>(W_out + (size_t)(j0 + jj) * ED + k);
#pragma unroll
        for (int tl = 0; tl < TPB2; ++tl) {
            const float4 e = *reinterpret_cast<const float4*>(E + tl * ED + k);
#pragma unroll
            for (int jj = 0; jj < 4; ++jj) {
                acc[tl][jj] = fmaf(wr[jj].x, e.x, acc[tl][jj]);
                acc[tl][jj] = fmaf(wr[jj].y, e.y, acc[tl][jj]);
                acc[tl][jj] = fmaf(wr[jj].z, e.z, acc[tl][jj]);
                acc[tl][jj] = fmaf(wr[jj].w, e.w, acc[tl][jj]);
            }
        }
    }

    const float4 bb = *reinterpret_cast<const float4*>(b_out + j0);
#pragma unroll
    for (int tl = 0; tl < TPB2; ++tl) {
        float4 r;
        r.x = acc[tl][0] + bb.x;
        r.y = acc[tl][1] + bb.y;
        r.z = acc[tl][2] + bb.z;
        r.w = acc[tl][3] + bb.w;
        *reinterpret_cast<float4*>(out + (size_t)(tg + tl) * OD + j0) = r;
    }
}

// ---------------------------------------------------------------------------

extern "C" void kernel_launch(void* const* d_in, const int* in_sizes, int n_in,
                              void* d_out, int out_size, void* d_ws, size_t ws_size,
                              hipStream_t stream)
{
    const int*   word_inputs  = (const int*)  d_in[0];
    const int*   char_ids     = (const int*)  d_in[1];
    const int*   char_lengths = (const int*)  d_in[2];
    const float* word_table   = (const float*)d_in[3];
    const float* char_table   = (const float*)d_in[4];
    const float* Wg           = (const float*)d_in[5];
    const float* bg           = (const float*)d_in[6];
    const float* Wp           = (const float*)d_in[7];
    const float* bp           = (const float*)d_in[8];
    const float* W_out        = (const float*)d_in[9];
    const float* b_out        = (const float*)d_in[10];

    float* out = (float*)d_out;
    unsigned short* char_repr = (unsigned short*)d_ws;              // 2 MB bf16
    uint4* Wpacked = (uint4*)((char*)d_ws + 2 * 1024 * 1024);       // 256 KB
    int*   sortbuf = (int*)((char*)d_ws + 2 * 1024 * 1024 + 256 * 1024);
    const int* order = sortbuf + 48;

    pack_weights<<<64, 256, 0, stream>>>(Wg, Wp, Wpacked);
    sort_zero<<<1, 64, 0, stream>>>(sortbuf);
    sort_hist<<<NTOK / 256, 256, 0, stream>>>(char_lengths, sortbuf);
    sort_prefix<<<1, 64, 0, stream>>>(sortbuf);
    sort_scatter_det<<<16, 256, 0, stream>>>(char_lengths, sortbuf);

    scan_mfma<<<NTOK / TW, 512, 0, stream>>>(char_ids, char_lengths, char_table,
                                             bg, bp, Wpacked, order, char_repr);
    out_gemm<<<NTOK / TPB2, 256, 0, stream>>>(word_inputs, word_table, char_repr,
                                              W_out, b_out, out);
}

// Round 11
// 402.508 us; speedup vs baseline: 2.6301x; 1.2754x over previous
//
#include <hip/hip_runtime.h>
#include <hip/hip_bf16.h>

#define NTOK 8192
#define SCC  16
#define CD   128
#define WD   512
#define OD   1024
#define ED   640   // WD + CD
#define TW   4     // tokens per scan workgroup
#define SP   132   // padded S row stride (floats): kills q*128 bank aliasing
#define ST   (SCC * SP)

typedef __attribute__((ext_vector_type(8))) short short8;
typedef __attribute__((ext_vector_type(4))) float f32x4;

__device__ __forceinline__ unsigned short f2bf(float f) {
    union { float f; unsigned u; } v; v.f = f;
    unsigned r = v.u + 0x7FFF + ((v.u >> 16) & 1);   // RNE
    return (unsigned short)(r >> 16);
}

// ---------------------------------------------------------------------------
// Deterministic stable counting sort of tokens by length (16 bins).
// ws ints: [0..15]=hist [16..31]=base [32..47]=unused [48..48+NTOK)=order
// ---------------------------------------------------------------------------
__global__ void sort_zero(int* s) { if (threadIdx.x < 48) s[threadIdx.x] = 0; }

__global__ void sort_hist(const int* __restrict__ lengths, int* __restrict__ s) {
    const int i = blockIdx.x * 256 + threadIdx.x;
    if (i < NTOK) atomicAdd(&s[lengths[i] - 1], 1);
}

__global__ void sort_prefix(int* s) {
    if (threadIdx.x == 0) {
        int acc = 0;
        for (int b = 0; b < 16; ++b) { s[16 + b] = acc; acc += s[b]; }
    }
}

// one block per bin; ballot-based stable rank — bit-deterministic every call
__global__ __launch_bounds__(256) void sort_scatter_det(
    const int* __restrict__ lengths, int* __restrict__ s)
{
    __shared__ int wsum[4];
    __shared__ int running;
    const int b   = blockIdx.x;
    const int tid = threadIdx.x;
    if (tid == 0) running = s[16 + b];
    __syncthreads();
    for (int c0 = 0; c0 < NTOK; c0 += 256) {
        const int i = c0 + tid;
        const bool f = (lengths[i] - 1 == b);
        const unsigned long long m = __ballot(f);
        const int wv = tid >> 6;
        if ((tid & 63) == 0) wsum[wv] = __popcll(m);
        __syncthreads();
        int excl = 0;
#pragma unroll
        for (int k = 0; k < 4; ++k) if (k < wv) excl += wsum[k];
        const int lanerank = __popcll(m & ((1ull << (tid & 63)) - 1ull));
        if (f) s[48 + running + excl + lanerank] = i;
        const int tot = wsum[0] + wsum[1] + wsum[2] + wsum[3];
        __syncthreads();
        if (tid == 0) running += tot;
        __syncthreads();
    }
}

// ---------------------------------------------------------------------------
// Kernel 0a: pack Wg(384x256)+Wp(128x256) fp32 -> bf16 B-fragment layout.
// lane l holds B[k=(l>>4)*8+e][n=l&15], e=0..7. n = c*128 + w*16 + (l&15).
// index: ((w*4+c)*8+kf)*64 + lane, entry = uint4 (8 bf16 along k).
// ---------------------------------------------------------------------------
__global__ __launch_bounds__(256) void pack_weights(
    const float* __restrict__ Wg, const float* __restrict__ Wp,
    uint4* __restrict__ packed)
{
    const int gid  = blockIdx.x * 256 + threadIdx.x;  // 0..16383
    const int lane = gid & 63;
    const int kf   = (gid >> 6) & 7;
    const int c    = (gid >> 9) & 3;
    const int w    = (gid >> 11) & 7;
    const int n    = c * 128 + w * 16 + (lane & 15);
    const int k0   = kf * 32 + (lane >> 4) * 8;
    const float* src = (n < 384) ? (Wg + n * 256 + k0) : (Wp + (n - 384) * 256 + k0);
    uint4 o;
    o.x = f2bf(src[0]) | ((unsigned)f2bf(src[1]) << 16);
    o.y = f2bf(src[2]) | ((unsigned)f2bf(src[3]) << 16);
    o.z = f2bf(src[4]) | ((unsigned)f2bf(src[5]) << 16);
    o.w = f2bf(src[6]) | ((unsigned)f2bf(src[7]) << 16);
    packed[gid] = o;
}

// ---------------------------------------------------------------------------
// Kernel 0b: pack W_out (1024x640) fp32 -> bf16 B-fragments.
// index: (nb*20 + kf)*64 + lane, nb = n>>4 (0..63), kf = 0..19.
// lane holds W_out[n = nb*16 + (l&15)][k = kf*32 + (l>>4)*8 + e].
// ---------------------------------------------------------------------------
__global__ __launch_bounds__(256) void pack_wout(
    const float* __restrict__ W_out, uint4* __restrict__ packed)
{
    const int gid  = blockIdx.x * 256 + threadIdx.x;  // 0..81919
    const int lane = gid & 63;
    const int kf   = (gid >> 6) % 20;
    const int nb   = (gid >> 6) / 20;
    const int n    = nb * 16 + (lane & 15);
    const int k0   = kf * 32 + (lane >> 4) * 8;
    const float* src = W_out + (size_t)n * ED + k0;
    uint4 o;
    o.x = f2bf(src[0]) | ((unsigned)f2bf(src[1]) << 16);
    o.y = f2bf(src[2]) | ((unsigned)f2bf(src[3]) << 16);
    o.z = f2bf(src[4]) | ((unsigned)f2bf(src[5]) << 16);
    o.w = f2bf(src[6]) | ((unsigned)f2bf(src[7]) << 16);
    packed[gid] = o;
}

// ---------------------------------------------------------------------------
// Kernel 1: MFMA gated pyramid scan. TW=4 sorted tokens/WG, 8 waves.
// Unified-register law (R5-R9): ~128 unified VGPR+AGPR budget per wave at
// this occupancy. Peak live < 128: acc[4][4]=64, b held 2-at-a-time.
// Static X layout r = p*4 + t; combine writes X directly. S stride padded
// to 132 floats; X-init reads rows p and p+1 EXPLICITLY (R10 bug: the old
// contiguous [left|right] float2 read crossed into the uninitialized pad).
// ---------------------------------------------------------------------------
__global__ __launch_bounds__(512, 2) void scan_mfma(
    const int*   __restrict__ char_ids,
    const int*   __restrict__ char_lengths,
    const float* __restrict__ char_table,
    const float* __restrict__ bg, const float* __restrict__ bp,
    const uint4* __restrict__ Wpacked,
    const int*   __restrict__ order,
    unsigned short* __restrict__ char_repr)
{
    __shared__ __align__(16) float S[TW * ST];                // 33 KB fp32 state
    __shared__ __align__(16) unsigned short X[64 * 256];      // 32 KB bf16, swizzled
    __shared__ int toksh[TW];
    __shared__ int Lsh[TW];

    const int tid  = threadIdx.x;
    const int lane = tid & 63;
    const int w    = tid >> 6;         // wave 0..7
    const int col  = lane & 15;
    const int q    = lane >> 4;        // 0..3

    if (tid < TW) {
        const int tok = order[blockIdx.x * TW + tid];
        toksh[tid] = tok;
        Lsh[tid]   = char_lengths[tok];
    }

    const int dj = w * 16 + col;
    float biasv[4];
    biasv[0] = bg[dj];
    biasv[1] = bg[128 + dj];
    biasv[2] = bg[256 + dj];
    biasv[3] = bp[dj];

    __syncthreads();

    // init state: S[t][c][d] = char_table[ids[tok[t]][c]][d]
    for (int i = tid; i < TW * SCC * (CD / 4); i += 512) {
        const int t   = i >> 9;
        const int rem = i & 511;
        const int c   = rem >> 5;
        const int d4  = rem & 31;
        const int id  = char_ids[toksh[t] * SCC + c];
        const float4 v = reinterpret_cast<const float4*>(char_table + id * CD)[d4];
        *reinterpret_cast<float4*>(S + t * ST + c * SP + d4 * 4) = v;
    }

    int L[TW];
#pragma unroll
    for (int t = 0; t < TW; ++t) L[t] = Lsh[t];
    const int maxL = max(max(L[0], L[1]), max(L[2], L[3]));

    __syncthreads();

    // init X once: row r=p*4+t = [S[t][p] | S[t][p+1]] bf16,
    // p=15 rows zero-filled. Left/right halves read EXPLICITLY (pad-safe).
    for (int i = tid; i < 64 * 128; i += 512) {
        const int r  = i >> 7;
        const int ku = i & 127;
        const int p  = r >> 2;
        const int t  = r & 3;
        unsigned u = 0u;
        if (p < 15) {
            float2 v;
            if (ku < 64)
                v = *reinterpret_cast<const float2*>(S + t * ST + p * SP + 2 * ku);
            else
                v = *reinterpret_cast<const float2*>(S + t * ST + (p + 1) * SP + 2 * (ku - 64));
            u = f2bf(v.x) | ((unsigned)f2bf(v.y) << 16);
        }
        int baddr = (r << 9) + (ku << 2);
        baddr ^= (r & 7) << 4;
        *reinterpret_cast<unsigned*>(reinterpret_cast<char*>(X) + baddr) = u;
    }
    __syncthreads();

    for (int len = 1; len < maxL; ++len) {
        const int Amax   = maxL - len;
        const int mfrags = (4 * Amax + 15) >> 4;       // <= 4

        f32x4 acc[4][4];   // [m-frag][chunk] -> 64 regs
#pragma unroll
        for (int m = 0; m < 4; ++m)
#pragma unroll
            for (int c = 0; c < 4; ++c) acc[m][c] = (f32x4){0.f, 0.f, 0.f, 0.f};

        // ---- MFMA phase: A from LDS X, B streamed from L2, 2 chunks live ----
#pragma unroll
        for (int kf = 0; kf < 8; ++kf) {
            const uint4* wp = Wpacked + (w * 32 + kf) * 64 + lane;
            short8 b0, b1;
            {
                union { uint4 u; short8 s; } cv;
                cv.u = wp[0];    b0 = cv.s;        // chunk 0
                cv.u = wp[512];  b1 = cv.s;        // chunk 1
            }
#pragma unroll
            for (int m = 0; m < 4; ++m) {
                if (m < mfrags) {
                    const int row = m * 16 + col;
                    int baddr = (row << 9) + (kf << 6) + (q << 4);
                    baddr ^= (row & 7) << 4;
                    const short8 a = *reinterpret_cast<const short8*>(
                        reinterpret_cast<const char*>(X) + baddr);
                    acc[m][0] = __builtin_amdgcn_mfma_f32_16x16x32_bf16(a, b0, acc[m][0], 0, 0, 0);
                    acc[m][1] = __builtin_amdgcn_mfma_f32_16x16x32_bf16(a, b1, acc[m][1], 0, 0, 0);
                }
            }
            {
                union { uint4 u; short8 s; } cv;
                cv.u = wp[1024]; b0 = cv.s;        // chunk 2
                cv.u = wp[1536]; b1 = cv.s;        // chunk 3
            }
#pragma unroll
            for (int m = 0; m < 4; ++m) {
                if (m < mfrags) {
                    const int row = m * 16 + col;
                    int baddr = (row << 9) + (kf << 6) + (q << 4);
                    baddr ^= (row & 7) << 4;
                    const short8 a = *reinterpret_cast<const short8*>(
                        reinterpret_cast<const char*>(X) + baddr);
                    acc[m][2] = __builtin_amdgcn_mfma_f32_16x16x32_bf16(a, b0, acc[m][2], 0, 0, 0);
                    acc[m][3] = __builtin_amdgcn_mfma_f32_16x16x32_bf16(a, b1, acc[m][3], 0, 0, 0);
                }
            }
        }

        // ---- combine: lane-local softmax + convex mix. t = i, p = m*4+q ----
#pragma unroll
        for (int m = 0; m < 4; ++m) {
            if (m < mfrags) {
                const int p = m * 4 + q;
#pragma unroll
                for (int i = 0; i < 4; ++i) {
                    const float g0 = acc[m][0][i] + biasv[0];
                    const float g1 = acc[m][1][i] + biasv[1];
                    const float g2 = acc[m][2][i] + biasv[2];
                    const float z  = acc[m][3][i] + biasv[3];
                    const float mx = fmaxf(fmaxf(g0, g1), g2);
                    const float e0 = __expf(g0 - mx);
                    const float e1 = __expf(g1 - mx);
                    const float e2 = __expf(g2 - mx);
                    const float left  = S[i * ST + p * SP + dj];
                    const float right = S[i * ST + (p + 1) * SP + dj];
                    const float inv = __builtin_amdgcn_rcpf(e0 + e1 + e2);
                    acc[m][0][i] = (e0 * left + e1 * right + e2 * z) * inv;
                }
            }
        }
        __syncthreads();   // all X-reads (MFMA) and S-reads (combine) done

        // ---- write phase: masked fp32 S + bf16 X (left @ p, right @ p-1) ----
#pragma unroll
        for (int m = 0; m < 4; ++m) {
            if (m < mfrags) {
                const int p = m * 4 + q;
#pragma unroll
                for (int i = 0; i < 4; ++i) {
                    const float val = acc[m][0][i];
                    if (p < L[i] - len) S[i * ST + p * SP + dj] = val;
                    const unsigned short bv = f2bf(val);
                    const int rl = m * 16 + q * 4 + i;          // row p*4+i
                    int bl = (rl << 9) + (dj << 1);
                    bl ^= (rl & 7) << 4;
                    *reinterpret_cast<unsigned short*>(
                        reinterpret_cast<char*>(X) + bl) = bv;
                    if (p >= 1) {
                        const int rr = rl - 4;                  // row (p-1)*4+i
                        int br = (rr << 9) + 256 + (dj << 1);
                        br ^= (rr & 7) << 4;
                        *reinterpret_cast<unsigned short*>(
                            reinterpret_cast<char*>(X) + br) = bv;
                    }
                }
            }
        }
        __syncthreads();
    }

    // char representation = S[t][0][:], stored bf16
    for (int i = tid; i < TW * CD; i += 512) {
        const int t = i >> 7, d = i & 127;
        char_repr[toksh[t] * CD + d] = f2bf(S[t * ST + d]);
    }
}

// ---------------------------------------------------------------------------
// Kernel 2: MFMA out-projection. out[t][j] = b_out[j] + emb[t].W_out[j].
// Grid = NTOK/16 tiles. 4 waves; wave w owns n in [w*256, w*256+256).
// emb tile (16 x 640) staged in LDS as bf16, XOR-swizzled; W_out streamed
// from the packed bf16 fragment buffer (L2-resident, 1.3 MB).
// acc[16] = 64 regs + a 4 + b 4 -> ~90 live, fits the 128 budget.
// ---------------------------------------------------------------------------
__global__ __launch_bounds__(256) void out_mfma(
    const int*   __restrict__ word_inputs,
    const float* __restrict__ word_table,
    const unsigned short* __restrict__ char_repr,   // bf16 bits
    const uint4* __restrict__ pwout,
    const float* __restrict__ b_out,
    float*       __restrict__ out)
{
    __shared__ __align__(16) unsigned short E[16 * ED];   // 20 KB, swizzled

    const int tg   = blockIdx.x * 16;
    const int tid  = threadIdx.x;
    const int lane = tid & 63;
    const int w    = tid >> 6;         // wave 0..3
    const int col  = lane & 15;
    const int q    = lane >> 4;

    // stage word part: 16 tokens x 512 dims as bf16 pairs
    for (int i = tid; i < 16 * 256; i += 256) {
        const int rt = i >> 8, kp = i & 255;     // dims 2kp, 2kp+1
        const float2 v = *reinterpret_cast<const float2*>(
            word_table + (size_t)word_inputs[tg + rt] * WD + 2 * kp);
        const unsigned u = f2bf(v.x) | ((unsigned)f2bf(v.y) << 16);
        int baddr = rt * 1280 + kp * 4;
        baddr ^= (rt & 7) << 4;
        *reinterpret_cast<unsigned*>(reinterpret_cast<char*>(E) + baddr) = u;
    }
    // stage char part: 16 tokens x 128 dims (already bf16)
    for (int i = tid; i < 16 * 64; i += 256) {
        const int rt = i >> 6, kp = i & 63;      // dims 512+2kp, 512+2kp+1
        const unsigned u = *reinterpret_cast<const unsigned*>(
            char_repr + (tg + rt) * CD + 2 * kp);
        int baddr = rt * 1280 + 1024 + kp * 4;
        baddr ^= (rt & 7) << 4;
        *reinterpret_cast<unsigned*>(reinterpret_cast<char*>(E) + baddr) = u;
    }
    __syncthreads();

    f32x4 acc[16];
#pragma unroll
    for (int nf = 0; nf < 16; ++nf) acc[nf] = (f32x4){0.f, 0.f, 0.f, 0.f};

#pragma unroll 4
    for (int kf = 0; kf < 20; ++kf) {
        // A: token row = col, k0 = kf*32 + q*8
        int ba = col * 1280 + kf * 64 + q * 16;
        ba ^= (col & 7) << 4;
        const short8 a = *reinterpret_cast<const short8*>(
            reinterpret_cast<const char*>(E) + ba);
#pragma unroll
        for (int nf = 0; nf < 16; ++nf) {
            const int nb = w * 16 + nf;
            union { uint4 u; short8 s; } cv;
            cv.u = pwout[(nb * 20 + kf) * 64 + lane];
            acc[nf] = __builtin_amdgcn_mfma_f32_16x16x32_bf16(a, cv.s, acc[nf], 0, 0, 0);
        }
    }

#pragma unroll
    for (int nf = 0; nf < 16; ++nf) {
        const int j = (w * 16 + nf) * 16 + col;
        const float bias = b_out[j];
#pragma unroll
        for (int i = 0; i < 4; ++i) {
            out[(size_t)(tg + q * 4 + i) * OD + j] = acc[nf][i] + bias;
        }
    }
}

// ---------------------------------------------------------------------------

extern "C" void kernel_launch(void* const* d_in, const int* in_sizes, int n_in,
                              void* d_out, int out_size, void* d_ws, size_t ws_size,
                              hipStream_t stream)
{
    const int*   word_inputs  = (const int*)  d_in[0];
    const int*   char_ids     = (const int*)  d_in[1];
    const int*   char_lengths = (const int*)  d_in[2];
    const float* word_table   = (const float*)d_in[3];
    const float* char_table   = (const float*)d_in[4];
    const float* Wg           = (const float*)d_in[5];
    const float* bg           = (const float*)d_in[6];
    const float* Wp           = (const float*)d_in[7];
    const float* bp           = (const float*)d_in[8];
    const float* W_out        = (const float*)d_in[9];
    const float* b_out        = (const float*)d_in[10];

    float* out = (float*)d_out;
    char* ws = (char*)d_ws;
    unsigned short* char_repr = (unsigned short*)ws;                 // 2 MB bf16
    uint4* Wpacked = (uint4*)(ws + 2 * 1024 * 1024);                 // 256 KB
    int*   sortbuf = (int*)(ws + 2 * 1024 * 1024 + 256 * 1024);      // 33 KB
    const int* order = sortbuf + 48;
    uint4* pwout = (uint4*)(ws + 2 * 1024 * 1024 + 256 * 1024 + 64 * 1024); // 1.3 MB

    pack_weights<<<64, 256, 0, stream>>>(Wg, Wp, Wpacked);
    pack_wout<<<320, 256, 0, stream>>>(W_out, pwout);
    sort_zero<<<1, 64, 0, stream>>>(sortbuf);
    sort_hist<<<NTOK / 256, 256, 0, stream>>>(char_lengths, sortbuf);
    sort_prefix<<<1, 64, 0, stream>>>(sortbuf);
    sort_scatter_det<<<16, 256, 0, stream>>>(char_lengths, sortbuf);

    scan_mfma<<<NTOK / TW, 512, 0, stream>>>(char_ids, char_lengths, char_table,
                                             bg, bp, Wpacked, order, char_repr);
    out_mfma<<<NTOK / 16, 256, 0, stream>>>(word_inputs, word_table, char_repr,
                                            pwout, b_out, out);
}

// Round 12
// 367.358 us; speedup vs baseline: 2.8818x; 1.0957x over previous
//
#include <hip/hip_runtime.h>
#include <hip/hip_bf16.h>

#define NTOK 8192
#define SCC  16
#define CD   128
#define WD   512
#define OD   1024
#define ED   640   // WD + CD
#define TW   4     // tokens per scan workgroup
#define SP   132   // padded S row stride (floats): kills q*128 bank aliasing
#define ST   (SCC * SP)

typedef __attribute__((ext_vector_type(8))) short short8;
typedef __attribute__((ext_vector_type(4))) float f32x4;

__device__ __forceinline__ unsigned short f2bf(float f) {
    union { float f; unsigned u; } v; v.f = f;
    unsigned r = v.u + 0x7FFF + ((v.u >> 16) & 1);   // RNE
    return (unsigned short)(r >> 16);
}

// ---------------------------------------------------------------------------
// Deterministic stable counting sort of tokens by length (16 bins).
// ws ints: [0..15]=hist [16..31]=base [32..47]=unused [48..48+NTOK)=order
// ---------------------------------------------------------------------------
__global__ void sort_zero(int* s) { if (threadIdx.x < 48) s[threadIdx.x] = 0; }

__global__ void sort_hist(const int* __restrict__ lengths, int* __restrict__ s) {
    const int i = blockIdx.x * 256 + threadIdx.x;
    if (i < NTOK) atomicAdd(&s[lengths[i] - 1], 1);
}

__global__ void sort_prefix(int* s) {
    if (threadIdx.x == 0) {
        int acc = 0;
        for (int b = 0; b < 16; ++b) { s[16 + b] = acc; acc += s[b]; }
    }
}

// one block per bin; ballot-based stable rank — bit-deterministic every call
__global__ __launch_bounds__(256) void sort_scatter_det(
    const int* __restrict__ lengths, int* __restrict__ s)
{
    __shared__ int wsum[4];
    __shared__ int running;
    const int b   = blockIdx.x;
    const int tid = threadIdx.x;
    if (tid == 0) running = s[16 + b];
    __syncthreads();
    for (int c0 = 0; c0 < NTOK; c0 += 256) {
        const int i = c0 + tid;
        const bool f = (lengths[i] - 1 == b);
        const unsigned long long m = __ballot(f);
        const int wv = tid >> 6;
        if ((tid & 63) == 0) wsum[wv] = __popcll(m);
        __syncthreads();
        int excl = 0;
#pragma unroll
        for (int k = 0; k < 4; ++k) if (k < wv) excl += wsum[k];
        const int lanerank = __popcll(m & ((1ull << (tid & 63)) - 1ull));
        if (f) s[48 + running + excl + lanerank] = i;
        const int tot = wsum[0] + wsum[1] + wsum[2] + wsum[3];
        __syncthreads();
        if (tid == 0) running += tot;
        __syncthreads();
    }
}

// ---------------------------------------------------------------------------
// Kernel 0a: pack Wg(384x256)+Wp(128x256) fp32 -> bf16 B-fragment layout.
// lane l holds B[k=(l>>4)*8+e][n=l&15], e=0..7. n = c*128 + w*16 + (l&15).
// index: ((w*4+c)*8+kf)*64 + lane, entry = uint4 (8 bf16 along k).
// ---------------------------------------------------------------------------
__global__ __launch_bounds__(256) void pack_weights(
    const float* __restrict__ Wg, const float* __restrict__ Wp,
    uint4* __restrict__ packed)
{
    const int gid  = blockIdx.x * 256 + threadIdx.x;  // 0..16383
    const int lane = gid & 63;
    const int kf   = (gid >> 6) & 7;
    const int c    = (gid >> 9) & 3;
    const int w    = (gid >> 11) & 7;
    const int n    = c * 128 + w * 16 + (lane & 15);
    const int k0   = kf * 32 + (lane >> 4) * 8;
    const float* src = (n < 384) ? (Wg + n * 256 + k0) : (Wp + (n - 384) * 256 + k0);
    uint4 o;
    o.x = f2bf(src[0]) | ((unsigned)f2bf(src[1]) << 16);
    o.y = f2bf(src[2]) | ((unsigned)f2bf(src[3]) << 16);
    o.z = f2bf(src[4]) | ((unsigned)f2bf(src[5]) << 16);
    o.w = f2bf(src[6]) | ((unsigned)f2bf(src[7]) << 16);
    packed[gid] = o;
}

// ---------------------------------------------------------------------------
// Kernel 0b: pack W_out (1024x640) fp32 -> bf16 B-fragments.
// index: (nb*20 + kf)*64 + lane, nb = n>>4 (0..63), kf = 0..19.
// ---------------------------------------------------------------------------
__global__ __launch_bounds__(256) void pack_wout(
    const float* __restrict__ W_out, uint4* __restrict__ packed)
{
    const int gid  = blockIdx.x * 256 + threadIdx.x;  // 0..81919
    const int lane = gid & 63;
    const int kf   = (gid >> 6) % 20;
    const int nb   = (gid >> 6) / 20;
    const int n    = nb * 16 + (lane & 15);
    const int k0   = kf * 32 + (lane >> 4) * 8;
    const float* src = W_out + (size_t)n * ED + k0;
    uint4 o;
    o.x = f2bf(src[0]) | ((unsigned)f2bf(src[1]) << 16);
    o.y = f2bf(src[2]) | ((unsigned)f2bf(src[3]) << 16);
    o.z = f2bf(src[4]) | ((unsigned)f2bf(src[5]) << 16);
    o.w = f2bf(src[6]) | ((unsigned)f2bf(src[7]) << 16);
    packed[gid] = o;
}

// ---------------------------------------------------------------------------
// Kernel 1: MFMA gated pyramid scan. TW=4 sorted tokens/WG, 8 waves.
// R11 post-mortem: fully-unrolled kf loop let the scheduler hoist later-kf
// weight loads -> many b-frags in flight -> spill (WRITE_SIZE 110 MB), and
// the chunk-split doubled X reads (bank conflicts up 60%). Fix: R4-shape
// inner loop (b[4] once/kf, a once/(kf,m), 16 MFMAs) + #pragma unroll 1 on
// the kf loop to pin the pipeline depth. Live ~108 < 128 budget.
// ---------------------------------------------------------------------------
__global__ __launch_bounds__(512, 2) void scan_mfma(
    const int*   __restrict__ char_ids,
    const int*   __restrict__ char_lengths,
    const float* __restrict__ char_table,
    const float* __restrict__ bg, const float* __restrict__ bp,
    const uint4* __restrict__ Wpacked,
    const int*   __restrict__ order,
    unsigned short* __restrict__ char_repr)
{
    __shared__ __align__(16) float S[TW * ST];                // 33 KB fp32 state
    __shared__ __align__(16) unsigned short X[64 * 256];      // 32 KB bf16, swizzled
    __shared__ int toksh[TW];
    __shared__ int Lsh[TW];

    const int tid  = threadIdx.x;
    const int lane = tid & 63;
    const int w    = tid >> 6;         // wave 0..7
    const int col  = lane & 15;
    const int q    = lane >> 4;        // 0..3

    if (tid < TW) {
        const int tok = order[blockIdx.x * TW + tid];
        toksh[tid] = tok;
        Lsh[tid]   = char_lengths[tok];
    }

    const int dj = w * 16 + col;
    float biasv[4];
    biasv[0] = bg[dj];
    biasv[1] = bg[128 + dj];
    biasv[2] = bg[256 + dj];
    biasv[3] = bp[dj];

    __syncthreads();

    // init state: S[t][c][d] = char_table[ids[tok[t]][c]][d]
    for (int i = tid; i < TW * SCC * (CD / 4); i += 512) {
        const int t   = i >> 9;
        const int rem = i & 511;
        const int c   = rem >> 5;
        const int d4  = rem & 31;
        const int id  = char_ids[toksh[t] * SCC + c];
        const float4 v = reinterpret_cast<const float4*>(char_table + id * CD)[d4];
        *reinterpret_cast<float4*>(S + t * ST + c * SP + d4 * 4) = v;
    }

    int L[TW];
#pragma unroll
    for (int t = 0; t < TW; ++t) L[t] = Lsh[t];
    const int maxL = max(max(L[0], L[1]), max(L[2], L[3]));

    __syncthreads();

    // init X once: row r=p*4+t = [S[t][p] | S[t][p+1]] bf16,
    // p=15 rows zero-filled. Left/right halves read EXPLICITLY (pad-safe).
    for (int i = tid; i < 64 * 128; i += 512) {
        const int r  = i >> 7;
        const int ku = i & 127;
        const int p  = r >> 2;
        const int t  = r & 3;
        unsigned u = 0u;
        if (p < 15) {
            float2 v;
            if (ku < 64)
                v = *reinterpret_cast<const float2*>(S + t * ST + p * SP + 2 * ku);
            else
                v = *reinterpret_cast<const float2*>(S + t * ST + (p + 1) * SP + 2 * (ku - 64));
            u = f2bf(v.x) | ((unsigned)f2bf(v.y) << 16);
        }
        int baddr = (r << 9) + (ku << 2);
        baddr ^= (r & 7) << 4;
        *reinterpret_cast<unsigned*>(reinterpret_cast<char*>(X) + baddr) = u;
    }
    __syncthreads();

    for (int len = 1; len < maxL; ++len) {
        const int Amax   = maxL - len;
        const int mfrags = (4 * Amax + 15) >> 4;       // <= 4

        f32x4 acc[4][4];   // [m-frag][chunk] -> 64 regs
#pragma unroll
        for (int m = 0; m < 4; ++m)
#pragma unroll
            for (int c = 0; c < 4; ++c) acc[m][c] = (f32x4){0.f, 0.f, 0.f, 0.f};

        // ---- MFMA phase: A from LDS X, B streamed from L2 ----
        // unroll 1: stop the scheduler from hoisting later-kf weight loads
        // (R11: that hoisting was the register spill).
#pragma unroll 1
        for (int kf = 0; kf < 8; ++kf) {
            const uint4* wp = Wpacked + (w * 32 + kf) * 64 + lane;
            short8 b[4];
#pragma unroll
            for (int c = 0; c < 4; ++c) {
                union { uint4 u; short8 s; } cv;
                cv.u = wp[c * 512];
                b[c] = cv.s;
            }
#pragma unroll
            for (int m = 0; m < 4; ++m) {
                if (m < mfrags) {
                    const int row = m * 16 + col;
                    int baddr = (row << 9) + (kf << 6) + (q << 4);
                    baddr ^= (row & 7) << 4;
                    const short8 a = *reinterpret_cast<const short8*>(
                        reinterpret_cast<const char*>(X) + baddr);
                    acc[m][0] = __builtin_amdgcn_mfma_f32_16x16x32_bf16(a, b[0], acc[m][0], 0, 0, 0);
                    acc[m][1] = __builtin_amdgcn_mfma_f32_16x16x32_bf16(a, b[1], acc[m][1], 0, 0, 0);
                    acc[m][2] = __builtin_amdgcn_mfma_f32_16x16x32_bf16(a, b[2], acc[m][2], 0, 0, 0);
                    acc[m][3] = __builtin_amdgcn_mfma_f32_16x16x32_bf16(a, b[3], acc[m][3], 0, 0, 0);
                }
            }
        }

        // ---- combine: lane-local softmax + convex mix. t = i, p = m*4+q ----
#pragma unroll
        for (int m = 0; m < 4; ++m) {
            if (m < mfrags) {
                const int p = m * 4 + q;
#pragma unroll
                for (int i = 0; i < 4; ++i) {
                    const float g0 = acc[m][0][i] + biasv[0];
                    const float g1 = acc[m][1][i] + biasv[1];
                    const float g2 = acc[m][2][i] + biasv[2];
                    const float z  = acc[m][3][i] + biasv[3];
                    const float mx = fmaxf(fmaxf(g0, g1), g2);
                    const float e0 = __expf(g0 - mx);
                    const float e1 = __expf(g1 - mx);
                    const float e2 = __expf(g2 - mx);
                    const float left  = S[i * ST + p * SP + dj];
                    const float right = S[i * ST + (p + 1) * SP + dj];
                    const float inv = __builtin_amdgcn_rcpf(e0 + e1 + e2);
                    acc[m][0][i] = (e0 * left + e1 * right + e2 * z) * inv;
                }
            }
        }
        __syncthreads();   // all X-reads (MFMA) and S-reads (combine) done

        // ---- write phase: masked fp32 S + bf16 X (left @ p, right @ p-1) ----
#pragma unroll
        for (int m = 0; m < 4; ++m) {
            if (m < mfrags) {
                const int p = m * 4 + q;
#pragma unroll
                for (int i = 0; i < 4; ++i) {
                    const float val = acc[m][0][i];
                    if (p < L[i] - len) S[i * ST + p * SP + dj] = val;
                    const unsigned short bv = f2bf(val);
                    const int rl = m * 16 + q * 4 + i;          // row p*4+i
                    int bl = (rl << 9) + (dj << 1);
                    bl ^= (rl & 7) << 4;
                    *reinterpret_cast<unsigned short*>(
                        reinterpret_cast<char*>(X) + bl) = bv;
                    if (p >= 1) {
                        const int rr = rl - 4;                  // row (p-1)*4+i
                        int br = (rr << 9) + 256 + (dj << 1);
                        br ^= (rr & 7) << 4;
                        *reinterpret_cast<unsigned short*>(
                            reinterpret_cast<char*>(X) + br) = bv;
                    }
                }
            }
        }
        __syncthreads();
    }

    // char representation = S[t][0][:], stored bf16
    for (int i = tid; i < TW * CD; i += 512) {
        const int t = i >> 7, d = i & 127;
        char_repr[toksh[t] * CD + d] = f2bf(S[t * ST + d]);
    }
}

// ---------------------------------------------------------------------------
// Kernel 2: MFMA out-projection. out[t][j] = b_out[j] + emb[t].W_out[j].
// ---------------------------------------------------------------------------
__global__ __launch_bounds__(256) void out_mfma(
    const int*   __restrict__ word_inputs,
    const float* __restrict__ word_table,
    const unsigned short* __restrict__ char_repr,   // bf16 bits
    const uint4* __restrict__ pwout,
    const float* __restrict__ b_out,
    float*       __restrict__ out)
{
    __shared__ __align__(16) unsigned short E[16 * ED];   // 20 KB, swizzled

    const int tg   = blockIdx.x * 16;
    const int tid  = threadIdx.x;
    const int lane = tid & 63;
    const int w    = tid >> 6;         // wave 0..3
    const int col  = lane & 15;
    const int q    = lane >> 4;

    // stage word part: 16 tokens x 512 dims as bf16 pairs
    for (int i = tid; i < 16 * 256; i += 256) {
        const int rt = i >> 8, kp = i & 255;     // dims 2kp, 2kp+1
        const float2 v = *reinterpret_cast<const float2*>(
            word_table + (size_t)word_inputs[tg + rt] * WD + 2 * kp);
        const unsigned u = f2bf(v.x) | ((unsigned)f2bf(v.y) << 16);
        int baddr = rt * 1280 + kp * 4;
        baddr ^= (rt & 7) << 4;
        *reinterpret_cast<unsigned*>(reinterpret_cast<char*>(E) + baddr) = u;
    }
    // stage char part: 16 tokens x 128 dims (already bf16)
    for (int i = tid; i < 16 * 64; i += 256) {
        const int rt = i >> 6, kp = i & 63;      // dims 512+2kp, 512+2kp+1
        const unsigned u = *reinterpret_cast<const unsigned*>(
            char_repr + (tg + rt) * CD + 2 * kp);
        int baddr = rt * 1280 + 1024 + kp * 4;
        baddr ^= (rt & 7) << 4;
        *reinterpret_cast<unsigned*>(reinterpret_cast<char*>(E) + baddr) = u;
    }
    __syncthreads();

    f32x4 acc[16];
#pragma unroll
    for (int nf = 0; nf < 16; ++nf) acc[nf] = (f32x4){0.f, 0.f, 0.f, 0.f};

#pragma unroll 4
    for (int kf = 0; kf < 20; ++kf) {
        // A: token row = col, k0 = kf*32 + q*8
        int ba = col * 1280 + kf * 64 + q * 16;
        ba ^= (col & 7) << 4;
        const short8 a = *reinterpret_cast<const short8*>(
            reinterpret_cast<const char*>(E) + ba);
#pragma unroll
        for (int nf = 0; nf < 16; ++nf) {
            const int nb = w * 16 + nf;
            union { uint4 u; short8 s; } cv;
            cv.u = pwout[(nb * 20 + kf) * 64 + lane];
            acc[nf] = __builtin_amdgcn_mfma_f32_16x16x32_bf16(a, cv.s, acc[nf], 0, 0, 0);
        }
    }

#pragma unroll
    for (int nf = 0; nf < 16; ++nf) {
        const int j = (w * 16 + nf) * 16 + col;
        const float bias = b_out[j];
#pragma unroll
        for (int i = 0; i < 4; ++i) {
            out[(size_t)(tg + q * 4 + i) * OD + j] = acc[nf][i] + bias;
        }
    }
}

// ---------------------------------------------------------------------------

extern "C" void kernel_launch(void* const* d_in, const int* in_sizes, int n_in,
                              void* d_out, int out_size, void* d_ws, size_t ws_size,
                              hipStream_t stream)
{
    const int*   word_inputs  = (const int*)  d_in[0];
    const int*   char_ids     = (const int*)  d_in[1];
    const int*   char_lengths = (const int*)  d_in[2];
    const float* word_table   = (const float*)d_in[3];
    const float* char_table   = (const float*)d_in[4];
    const float* Wg           = (const float*)d_in[5];
    const float* bg           = (const float*)d_in[6];
    const float* Wp           = (const float*)d_in[7];
    const float* bp           = (const float*)d_in[8];
    const float* W_out        = (const float*)d_in[9];
    const float* b_out        = (const float*)d_in[10];

    float* out = (float*)d_out;
    char* ws = (char*)d_ws;
    unsigned short* char_repr = (unsigned short*)ws;                 // 2 MB bf16
    uint4* Wpacked = (uint4*)(ws + 2 * 1024 * 1024);                 // 256 KB
    int*   sortbuf = (int*)(ws + 2 * 1024 * 1024 + 256 * 1024);      // 33 KB
    const int* order = sortbuf + 48;
    uint4* pwout = (uint4*)(ws + 2 * 1024 * 1024 + 256 * 1024 + 64 * 1024); // 1.3 MB

    pack_weights<<<64, 256, 0, stream>>>(Wg, Wp, Wpacked);
    pack_wout<<<320, 256, 0, stream>>>(W_out, pwout);
    sort_zero<<<1, 64, 0, stream>>>(sortbuf);
    sort_hist<<<NTOK / 256, 256, 0, stream>>>(char_lengths, sortbuf);
    sort_prefix<<<1, 64, 0, stream>>>(sortbuf);
    sort_scatter_det<<<16, 256, 0, stream>>>(char_lengths, sortbuf);

    scan_mfma<<<NTOK / TW, 512, 0, stream>>>(char_ids, char_lengths, char_table,
                                             bg, bp, Wpacked, order, char_repr);
    out_mfma<<<NTOK / 16, 256, 0, stream>>>(word_inputs, word_table, char_repr,
                                            pwout, b_out, out);
}

// Round 13
// 342.609 us; speedup vs baseline: 3.0900x; 1.0722x over previous
//
#include <hip/hip_runtime.h>
#include <hip/hip_bf16.h>

#define NTOK 8192
#define SCC  16
#define CD   128
#define WD   512
#define OD   1024
#define ED   640   // WD + CD
#define TW   4     // tokens per scan workgroup
#define SP   132   // padded S row stride (floats): kills q*128 bank aliasing
#define ST   (SCC * SP)

typedef __attribute__((ext_vector_type(8))) short short8;
typedef __attribute__((ext_vector_type(4))) float f32x4;

__device__ __forceinline__ unsigned short f2bf(float f) {
    union { float f; unsigned u; } v; v.f = f;
    unsigned r = v.u + 0x7FFF + ((v.u >> 16) & 1);   // RNE
    return (unsigned short)(r >> 16);
}

// ---------------------------------------------------------------------------
// Deterministic stable counting sort of tokens by length (16 bins).
// ws ints: [0..15]=hist [16..31]=base [32..47]=unused [48..48+NTOK)=order
// ---------------------------------------------------------------------------
__global__ void sort_zero(int* s) { if (threadIdx.x < 48) s[threadIdx.x] = 0; }

__global__ void sort_hist(const int* __restrict__ lengths, int* __restrict__ s) {
    const int i = blockIdx.x * 256 + threadIdx.x;
    if (i < NTOK) atomicAdd(&s[lengths[i] - 1], 1);
}

__global__ void sort_prefix(int* s) {
    if (threadIdx.x == 0) {
        int acc = 0;
        for (int b = 0; b < 16; ++b) { s[16 + b] = acc; acc += s[b]; }
    }
}

// one block per bin; ballot-based stable rank — bit-deterministic every call
__global__ __launch_bounds__(256) void sort_scatter_det(
    const int* __restrict__ lengths, int* __restrict__ s)
{
    __shared__ int wsum[4];
    __shared__ int running;
    const int b   = blockIdx.x;
    const int tid = threadIdx.x;
    if (tid == 0) running = s[16 + b];
    __syncthreads();
    for (int c0 = 0; c0 < NTOK; c0 += 256) {
        const int i = c0 + tid;
        const bool f = (lengths[i] - 1 == b);
        const unsigned long long m = __ballot(f);
        const int wv = tid >> 6;
        if ((tid & 63) == 0) wsum[wv] = __popcll(m);
        __syncthreads();
        int excl = 0;
#pragma unroll
        for (int k = 0; k < 4; ++k) if (k < wv) excl += wsum[k];
        const int lanerank = __popcll(m & ((1ull << (tid & 63)) - 1ull));
        if (f) s[48 + running + excl + lanerank] = i;
        const int tot = wsum[0] + wsum[1] + wsum[2] + wsum[3];
        __syncthreads();
        if (tid == 0) running += tot;
        __syncthreads();
    }
}

// ---------------------------------------------------------------------------
// Kernel 0a: pack Wg(384x256)+Wp(128x256) fp32 -> bf16 B-fragment layout.
// lane l holds B[k=(l>>4)*8+e][n=l&15], e=0..7. n = c*128 + w*16 + (l&15).
// index: ((w*4+c)*8+kf)*64 + lane, entry = uint4 (8 bf16 along k).
// ---------------------------------------------------------------------------
__global__ __launch_bounds__(256) void pack_weights(
    const float* __restrict__ Wg, const float* __restrict__ Wp,
    uint4* __restrict__ packed)
{
    const int gid  = blockIdx.x * 256 + threadIdx.x;  // 0..16383
    const int lane = gid & 63;
    const int kf   = (gid >> 6) & 7;
    const int c    = (gid >> 9) & 3;
    const int w    = (gid >> 11) & 7;
    const int n    = c * 128 + w * 16 + (lane & 15);
    const int k0   = kf * 32 + (lane >> 4) * 8;
    const float* src = (n < 384) ? (Wg + n * 256 + k0) : (Wp + (n - 384) * 256 + k0);
    uint4 o;
    o.x = f2bf(src[0]) | ((unsigned)f2bf(src[1]) << 16);
    o.y = f2bf(src[2]) | ((unsigned)f2bf(src[3]) << 16);
    o.z = f2bf(src[4]) | ((unsigned)f2bf(src[5]) << 16);
    o.w = f2bf(src[6]) | ((unsigned)f2bf(src[7]) << 16);
    packed[gid] = o;
}

// ---------------------------------------------------------------------------
// Kernel 0b: pack W_out (1024x640) fp32 -> bf16 B-fragments.
// index: (nb*20 + kf)*64 + lane, nb = n>>4 (0..63), kf = 0..19.
// ---------------------------------------------------------------------------
__global__ __launch_bounds__(256) void pack_wout(
    const float* __restrict__ W_out, uint4* __restrict__ packed)
{
    const int gid  = blockIdx.x * 256 + threadIdx.x;  // 0..81919
    const int lane = gid & 63;
    const int kf   = (gid >> 6) % 20;
    const int nb   = (gid >> 6) / 20;
    const int n    = nb * 16 + (lane & 15);
    const int k0   = kf * 32 + (lane >> 4) * 8;
    const float* src = W_out + (size_t)n * ED + k0;
    uint4 o;
    o.x = f2bf(src[0]) | ((unsigned)f2bf(src[1]) << 16);
    o.y = f2bf(src[2]) | ((unsigned)f2bf(src[3]) << 16);
    o.z = f2bf(src[4]) | ((unsigned)f2bf(src[5]) << 16);
    o.w = f2bf(src[6]) | ((unsigned)f2bf(src[7]) << 16);
    packed[gid] = o;
}

// ---------------------------------------------------------------------------
// Kernel 1: MFMA gated pyramid scan. TW=4 sorted tokens/WG, 8 waves.
// R12 was latency-bound: unroll-1 serialized 8 kf iterations x ~300cy L2
// latency. R13: depth-2 ping-pong pipeline (bA/bB) + kf=0 fragments pinned
// in registers across the len-loop (weights are step-invariant). Arch live
// ~110-124, inside the proven no-spill budget.
// ---------------------------------------------------------------------------
#define LOAD_B(DST, KF)                                                     \
    {                                                                       \
        const uint4* wp_ = Wpacked + (w * 32 + (KF)) * 64 + lane;           \
        union { uint4 u; short8 s; } cv0, cv1, cv2, cv3;                    \
        cv0.u = wp_[0];    DST[0] = cv0.s;                                  \
        cv1.u = wp_[512];  DST[1] = cv1.s;                                  \
        cv2.u = wp_[1024]; DST[2] = cv2.s;                                  \
        cv3.u = wp_[1536]; DST[3] = cv3.s;                                  \
    }

#define MFMA_PHASE(BV, KF)                                                  \
    {                                                                       \
        _Pragma("unroll")                                                   \
        for (int m_ = 0; m_ < 4; ++m_) {                                    \
            if (m_ < mfrags) {                                              \
                const int row_ = m_ * 16 + col;                             \
                int ba_ = (row_ << 9) + ((KF) << 6) + (q << 4);             \
                ba_ ^= (row_ & 7) << 4;                                     \
                const short8 a_ = *reinterpret_cast<const short8*>(         \
                    reinterpret_cast<const char*>(X) + ba_);                \
                acc[m_][0] = __builtin_amdgcn_mfma_f32_16x16x32_bf16(a_, BV[0], acc[m_][0], 0, 0, 0); \
                acc[m_][1] = __builtin_amdgcn_mfma_f32_16x16x32_bf16(a_, BV[1], acc[m_][1], 0, 0, 0); \
                acc[m_][2] = __builtin_amdgcn_mfma_f32_16x16x32_bf16(a_, BV[2], acc[m_][2], 0, 0, 0); \
                acc[m_][3] = __builtin_amdgcn_mfma_f32_16x16x32_bf16(a_, BV[3], acc[m_][3], 0, 0, 0); \
            }                                                               \
        }                                                                   \
    }

__global__ __launch_bounds__(512, 2) void scan_mfma(
    const int*   __restrict__ char_ids,
    const int*   __restrict__ char_lengths,
    const float* __restrict__ char_table,
    const float* __restrict__ bg, const float* __restrict__ bp,
    const uint4* __restrict__ Wpacked,
    const int*   __restrict__ order,
    unsigned short* __restrict__ char_repr)
{
    __shared__ __align__(16) float S[TW * ST];                // 33 KB fp32 state
    __shared__ __align__(16) unsigned short X[64 * 256];      // 32 KB bf16, swizzled
    __shared__ int toksh[TW];
    __shared__ int Lsh[TW];

    const int tid  = threadIdx.x;
    const int lane = tid & 63;
    const int w    = tid >> 6;         // wave 0..7
    const int col  = lane & 15;
    const int q    = lane >> 4;        // 0..3

    if (tid < TW) {
        const int tok = order[blockIdx.x * TW + tid];
        toksh[tid] = tok;
        Lsh[tid]   = char_lengths[tok];
    }

    const int dj = w * 16 + col;
    float biasv[4];
    biasv[0] = bg[dj];
    biasv[1] = bg[128 + dj];
    biasv[2] = bg[256 + dj];
    biasv[3] = bp[dj];

    // pinned kf=0 weight fragments (step-invariant, loaded once)
    short8 bpin[4];
    LOAD_B(bpin, 0);

    __syncthreads();

    // init state: S[t][c][d] = char_table[ids[tok[t]][c]][d]
    for (int i = tid; i < TW * SCC * (CD / 4); i += 512) {
        const int t   = i >> 9;
        const int rem = i & 511;
        const int c   = rem >> 5;
        const int d4  = rem & 31;
        const int id  = char_ids[toksh[t] * SCC + c];
        const float4 v = reinterpret_cast<const float4*>(char_table + id * CD)[d4];
        *reinterpret_cast<float4*>(S + t * ST + c * SP + d4 * 4) = v;
    }

    int L[TW];
#pragma unroll
    for (int t = 0; t < TW; ++t) L[t] = Lsh[t];
    const int maxL = max(max(L[0], L[1]), max(L[2], L[3]));

    __syncthreads();

    // init X once: row r=p*4+t = [S[t][p] | S[t][p+1]] bf16,
    // p=15 rows zero-filled. Left/right halves read EXPLICITLY (pad-safe).
    for (int i = tid; i < 64 * 128; i += 512) {
        const int r  = i >> 7;
        const int ku = i & 127;
        const int p  = r >> 2;
        const int t  = r & 3;
        unsigned u = 0u;
        if (p < 15) {
            float2 v;
            if (ku < 64)
                v = *reinterpret_cast<const float2*>(S + t * ST + p * SP + 2 * ku);
            else
                v = *reinterpret_cast<const float2*>(S + t * ST + (p + 1) * SP + 2 * (ku - 64));
            u = f2bf(v.x) | ((unsigned)f2bf(v.y) << 16);
        }
        int baddr = (r << 9) + (ku << 2);
        baddr ^= (r & 7) << 4;
        *reinterpret_cast<unsigned*>(reinterpret_cast<char*>(X) + baddr) = u;
    }
    __syncthreads();

    for (int len = 1; len < maxL; ++len) {
        const int Amax   = maxL - len;
        const int mfrags = (4 * Amax + 15) >> 4;       // <= 4

        f32x4 acc[4][4];   // [m-frag][chunk] -> 64 regs (accumulator class)
#pragma unroll
        for (int m = 0; m < 4; ++m)
#pragma unroll
            for (int c = 0; c < 4; ++c) acc[m][c] = (f32x4){0.f, 0.f, 0.f, 0.f};

        // ---- MFMA phase: depth-2 pipelined B loads, kf=0 pinned ----
        short8 bA[4], bB[4];
        LOAD_B(bA, 1);
        MFMA_PHASE(bpin, 0);
#pragma unroll 1
        for (int kh = 0; kh < 3; ++kh) {      // kf pairs: (1,2),(3,4),(5,6)->7
            LOAD_B(bB, 2 + 2 * kh);
            MFMA_PHASE(bA, 1 + 2 * kh);
            LOAD_B(bA, 3 + 2 * kh);           // kh=2 loads kf=7
            MFMA_PHASE(bB, 2 + 2 * kh);
        }
        MFMA_PHASE(bA, 7);

        // ---- combine: lane-local softmax + convex mix. t = i, p = m*4+q ----
#pragma unroll
        for (int m = 0; m < 4; ++m) {
            if (m < mfrags) {
                const int p = m * 4 + q;
#pragma unroll
                for (int i = 0; i < 4; ++i) {
                    const float g0 = acc[m][0][i] + biasv[0];
                    const float g1 = acc[m][1][i] + biasv[1];
                    const float g2 = acc[m][2][i] + biasv[2];
                    const float z  = acc[m][3][i] + biasv[3];
                    const float mx = fmaxf(fmaxf(g0, g1), g2);
                    const float e0 = __expf(g0 - mx);
                    const float e1 = __expf(g1 - mx);
                    const float e2 = __expf(g2 - mx);
                    const float left  = S[i * ST + p * SP + dj];
                    const float right = S[i * ST + (p + 1) * SP + dj];
                    const float inv = __builtin_amdgcn_rcpf(e0 + e1 + e2);
                    acc[m][0][i] = (e0 * left + e1 * right + e2 * z) * inv;
                }
            }
        }
        __syncthreads();   // all X-reads (MFMA) and S-reads (combine) done

        // ---- write phase: masked fp32 S + bf16 X (left @ p, right @ p-1) ----
#pragma unroll
        for (int m = 0; m < 4; ++m) {
            if (m < mfrags) {
                const int p = m * 4 + q;
#pragma unroll
                for (int i = 0; i < 4; ++i) {
                    const float val = acc[m][0][i];
                    if (p < L[i] - len) S[i * ST + p * SP + dj] = val;
                    const unsigned short bv = f2bf(val);
                    const int rl = m * 16 + q * 4 + i;          // row p*4+i
                    int bl = (rl << 9) + (dj << 1);
                    bl ^= (rl & 7) << 4;
                    *reinterpret_cast<unsigned short*>(
                        reinterpret_cast<char*>(X) + bl) = bv;
                    if (p >= 1) {
                        const int rr = rl - 4;                  // row (p-1)*4+i
                        int br = (rr << 9) + 256 + (dj << 1);
                        br ^= (rr & 7) << 4;
                        *reinterpret_cast<unsigned short*>(
                            reinterpret_cast<char*>(X) + br) = bv;
                    }
                }
            }
        }
        __syncthreads();
    }

    // char representation = S[t][0][:], stored bf16
    for (int i = tid; i < TW * CD; i += 512) {
        const int t = i >> 7, d = i & 127;
        char_repr[toksh[t] * CD + d] = f2bf(S[t * ST + d]);
    }
}

// ---------------------------------------------------------------------------
// Kernel 2: MFMA out-projection. out[t][j] = b_out[j] + emb[t].W_out[j].
// ---------------------------------------------------------------------------
__global__ __launch_bounds__(256) void out_mfma(
    const int*   __restrict__ word_inputs,
    const float* __restrict__ word_table,
    const unsigned short* __restrict__ char_repr,   // bf16 bits
    const uint4* __restrict__ pwout,
    const float* __restrict__ b_out,
    float*       __restrict__ out)
{
    __shared__ __align__(16) unsigned short E[16 * ED];   // 20 KB, swizzled

    const int tg   = blockIdx.x * 16;
    const int tid  = threadIdx.x;
    const int lane = tid & 63;
    const int w    = tid >> 6;         // wave 0..3
    const int col  = lane & 15;
    const int q    = lane >> 4;

    // stage word part: 16 tokens x 512 dims as bf16 pairs
    for (int i = tid; i < 16 * 256; i += 256) {
        const int rt = i >> 8, kp = i & 255;     // dims 2kp, 2kp+1
        const float2 v = *reinterpret_cast<const float2*>(
            word_table + (size_t)word_inputs[tg + rt] * WD + 2 * kp);
        const unsigned u = f2bf(v.x) | ((unsigned)f2bf(v.y) << 16);
        int baddr = rt * 1280 + kp * 4;
        baddr ^= (rt & 7) << 4;
        *reinterpret_cast<unsigned*>(reinterpret_cast<char*>(E) + baddr) = u;
    }
    // stage char part: 16 tokens x 128 dims (already bf16)
    for (int i = tid; i < 16 * 64; i += 256) {
        const int rt = i >> 6, kp = i & 63;      // dims 512+2kp, 512+2kp+1
        const unsigned u = *reinterpret_cast<const unsigned*>(
            char_repr + (tg + rt) * CD + 2 * kp);
        int baddr = rt * 1280 + 1024 + kp * 4;
        baddr ^= (rt & 7) << 4;
        *reinterpret_cast<unsigned*>(reinterpret_cast<char*>(E) + baddr) = u;
    }
    __syncthreads();

    f32x4 acc[16];
#pragma unroll
    for (int nf = 0; nf < 16; ++nf) acc[nf] = (f32x4){0.f, 0.f, 0.f, 0.f};

#pragma unroll 4
    for (int kf = 0; kf < 20; ++kf) {
        // A: token row = col, k0 = kf*32 + q*8
        int ba = col * 1280 + kf * 64 + q * 16;
        ba ^= (col & 7) << 4;
        const short8 a = *reinterpret_cast<const short8*>(
            reinterpret_cast<const char*>(E) + ba);
#pragma unroll
        for (int nf = 0; nf < 16; ++nf) {
            const int nb = w * 16 + nf;
            union { uint4 u; short8 s; } cv;
            cv.u = pwout[(nb * 20 + kf) * 64 + lane];
            acc[nf] = __builtin_amdgcn_mfma_f32_16x16x32_bf16(a, cv.s, acc[nf], 0, 0, 0);
        }
    }

#pragma unroll
    for (int nf = 0; nf < 16; ++nf) {
        const int j = (w * 16 + nf) * 16 + col;
        const float bias = b_out[j];
#pragma unroll
        for (int i = 0; i < 4; ++i) {
            out[(size_t)(tg + q * 4 + i) * OD + j] = acc[nf][i] + bias;
        }
    }
}

// ---------------------------------------------------------------------------

extern "C" void kernel_launch(void* const* d_in, const int* in_sizes, int n_in,
                              void* d_out, int out_size, void* d_ws, size_t ws_size,
                              hipStream_t stream)
{
    const int*   word_inputs  = (const int*)  d_in[0];
    const int*   char_ids     = (const int*)  d_in[1];
    const int*   char_lengths = (const int*)  d_in[2];
    const float* word_table   = (const float*)d_in[3];
    const float* char_table   = (const float*)d_in[4];
    const float* Wg           = (const float*)d_in[5];
    const float* bg           = (const float*)d_in[6];
    const float* Wp           = (const float*)d_in[7];
    const float* bp           = (const float*)d_in[8];
    const float* W_out        = (const float*)d_in[9];
    const float* b_out        = (const float*)d_in[10];

    float* out = (float*)d_out;
    char* ws = (char*)d_ws;
    unsigned short* char_repr = (unsigned short*)ws;                 // 2 MB bf16
    uint4* Wpacked = (uint4*)(ws + 2 * 1024 * 1024);                 // 256 KB
    int*   sortbuf = (int*)(ws + 2 * 1024 * 1024 + 256 * 1024);      // 33 KB
    const int* order = sortbuf + 48;
    uint4* pwout = (uint4*)(ws + 2 * 1024 * 1024 + 256 * 1024 + 64 * 1024); // 1.3 MB

    pack_weights<<<64, 256, 0, stream>>>(Wg, Wp, Wpacked);
    pack_wout<<<320, 256, 0, stream>>>(W_out, pwout);
    sort_zero<<<1, 64, 0, stream>>>(sortbuf);
    sort_hist<<<NTOK / 256, 256, 0, stream>>>(char_lengths, sortbuf);
    sort_prefix<<<1, 64, 0, stream>>>(sortbuf);
    sort_scatter_det<<<16, 256, 0, stream>>>(char_lengths, sortbuf);

    scan_mfma<<<NTOK / TW, 512, 0, stream>>>(char_ids, char_lengths, char_table,
                                             bg, bp, Wpacked, order, char_repr);
    out_mfma<<<NTOK / 16, 256, 0, stream>>>(word_inputs, word_table, char_repr,
                                            pwout, b_out, out);
}

// Round 14
// 309.350 us; speedup vs baseline: 3.4222x; 1.1075x over previous
//
#include <hip/hip_runtime.h>
#include <hip/hip_bf16.h>

#define NTOK 8192
#define SCC  16
#define CD   128
#define WD   512
#define OD   1024
#define ED   640   // WD + CD
#define TW   4     // tokens per scan workgroup
#define SP   132   // padded S row stride (floats): kills q*128 bank aliasing
#define ST   (SCC * SP)

typedef __attribute__((ext_vector_type(8))) short short8;
typedef __attribute__((ext_vector_type(4))) float f32x4;

__device__ __forceinline__ unsigned short f2bf(float f) {
    union { float f; unsigned u; } v; v.f = f;
    unsigned r = v.u + 0x7FFF + ((v.u >> 16) & 1);   // RNE
    return (unsigned short)(r >> 16);
}

// ---------------------------------------------------------------------------
// Deterministic stable counting sort of tokens by length, LONGEST FIRST.
// R13 post-mortem: ascending order put all 15-step WGs at the dispatch tail
// (OccupancyPercent 21%). LPT order packs short WGs into the tail instead.
// ws ints: [0..15]=hist [16..31]=base [32..47]=unused [48..48+NTOK)=order
// ---------------------------------------------------------------------------
__global__ void sort_zero(int* s) { if (threadIdx.x < 48) s[threadIdx.x] = 0; }

__global__ void sort_hist(const int* __restrict__ lengths, int* __restrict__ s) {
    const int i = blockIdx.x * 256 + threadIdx.x;
    if (i < NTOK) atomicAdd(&s[lengths[i] - 1], 1);
}

__global__ void sort_prefix(int* s) {
    if (threadIdx.x == 0) {
        int acc = 0;
        for (int b = 15; b >= 0; --b) { s[16 + b] = acc; acc += s[b]; }  // LPT
    }
}

// one block per bin; ballot-based stable rank — bit-deterministic every call
__global__ __launch_bounds__(256) void sort_scatter_det(
    const int* __restrict__ lengths, int* __restrict__ s)
{
    __shared__ int wsum[4];
    __shared__ int running;
    const int b   = blockIdx.x;
    const int tid = threadIdx.x;
    if (tid == 0) running = s[16 + b];
    __syncthreads();
    for (int c0 = 0; c0 < NTOK; c0 += 256) {
        const int i = c0 + tid;
        const bool f = (lengths[i] - 1 == b);
        const unsigned long long m = __ballot(f);
        const int wv = tid >> 6;
        if ((tid & 63) == 0) wsum[wv] = __popcll(m);
        __syncthreads();
        int excl = 0;
#pragma unroll
        for (int k = 0; k < 4; ++k) if (k < wv) excl += wsum[k];
        const int lanerank = __popcll(m & ((1ull << (tid & 63)) - 1ull));
        if (f) s[48 + running + excl + lanerank] = i;
        const int tot = wsum[0] + wsum[1] + wsum[2] + wsum[3];
        __syncthreads();
        if (tid == 0) running += tot;
        __syncthreads();
    }
}

// ---------------------------------------------------------------------------
// Kernel 0a: pack Wg(384x256)+Wp(128x256) fp32 -> bf16 B-fragment layout.
// lane l holds B[k=(l>>4)*8+e][n=l&15], e=0..7. n = c*128 + w*16 + (l&15).
// index: ((w*4+c)*8+kf)*64 + lane, entry = uint4 (8 bf16 along k).
// ---------------------------------------------------------------------------
__global__ __launch_bounds__(256) void pack_weights(
    const float* __restrict__ Wg, const float* __restrict__ Wp,
    uint4* __restrict__ packed)
{
    const int gid  = blockIdx.x * 256 + threadIdx.x;  // 0..16383
    const int lane = gid & 63;
    const int kf   = (gid >> 6) & 7;
    const int c    = (gid >> 9) & 3;
    const int w    = (gid >> 11) & 7;
    const int n    = c * 128 + w * 16 + (lane & 15);
    const int k0   = kf * 32 + (lane >> 4) * 8;
    const float* src = (n < 384) ? (Wg + n * 256 + k0) : (Wp + (n - 384) * 256 + k0);
    uint4 o;
    o.x = f2bf(src[0]) | ((unsigned)f2bf(src[1]) << 16);
    o.y = f2bf(src[2]) | ((unsigned)f2bf(src[3]) << 16);
    o.z = f2bf(src[4]) | ((unsigned)f2bf(src[5]) << 16);
    o.w = f2bf(src[6]) | ((unsigned)f2bf(src[7]) << 16);
    packed[gid] = o;
}

// ---------------------------------------------------------------------------
// Kernel 0b: pack W_out (1024x640) fp32 -> bf16 B-fragments.
// index: (nb*20 + kf)*64 + lane, nb = n>>4 (0..63), kf = 0..19.
// ---------------------------------------------------------------------------
__global__ __launch_bounds__(256) void pack_wout(
    const float* __restrict__ W_out, uint4* __restrict__ packed)
{
    const int gid  = blockIdx.x * 256 + threadIdx.x;  // 0..81919
    const int lane = gid & 63;
    const int kf   = (gid >> 6) % 20;
    const int nb   = (gid >> 6) / 20;
    const int n    = nb * 16 + (lane & 15);
    const int k0   = kf * 32 + (lane >> 4) * 8;
    const float* src = W_out + (size_t)n * ED + k0;
    uint4 o;
    o.x = f2bf(src[0]) | ((unsigned)f2bf(src[1]) << 16);
    o.y = f2bf(src[2]) | ((unsigned)f2bf(src[3]) << 16);
    o.z = f2bf(src[4]) | ((unsigned)f2bf(src[5]) << 16);
    o.w = f2bf(src[6]) | ((unsigned)f2bf(src[7]) << 16);
    packed[gid] = o;
}

// ---------------------------------------------------------------------------
// Kernel 1: MFMA gated pyramid scan. TW=4 LPT-sorted tokens/WG, 8 waves.
// Depth-2 ping-pong pipeline for B loads; kf=0 AND kf=1 pinned in registers
// across the len-loop (weights step-invariant). Arch live ~116 < 128 budget
// (R5-R12 law). Softmax computed without max-subtraction: |g| <~ 1 by weight
// scaling, exp cannot overflow, softmax is shift-invariant.
// ---------------------------------------------------------------------------
#define LOAD_B(DST, KF)                                                     \
    {                                                                       \
        const uint4* wp_ = Wpacked + (w * 32 + (KF)) * 64 + lane;           \
        union { uint4 u; short8 s; } cv0, cv1, cv2, cv3;                    \
        cv0.u = wp_[0];    DST[0] = cv0.s;                                  \
        cv1.u = wp_[512];  DST[1] = cv1.s;                                  \
        cv2.u = wp_[1024]; DST[2] = cv2.s;                                  \
        cv3.u = wp_[1536]; DST[3] = cv3.s;                                  \
    }

#define MFMA_PHASE(BV, KF)                                                  \
    {                                                                       \
        _Pragma("unroll")                                                   \
        for (int m_ = 0; m_ < 4; ++m_) {                                    \
            if (m_ < mfrags) {                                              \
                const int row_ = m_ * 16 + col;                             \
                int ba_ = (row_ << 9) + ((KF) << 6) + (q << 4);             \
                ba_ ^= (row_ & 7) << 4;                                     \
                const short8 a_ = *reinterpret_cast<const short8*>(         \
                    reinterpret_cast<const char*>(X) + ba_);                \
                acc[m_][0] = __builtin_amdgcn_mfma_f32_16x16x32_bf16(a_, BV[0], acc[m_][0], 0, 0, 0); \
                acc[m_][1] = __builtin_amdgcn_mfma_f32_16x16x32_bf16(a_, BV[1], acc[m_][1], 0, 0, 0); \
                acc[m_][2] = __builtin_amdgcn_mfma_f32_16x16x32_bf16(a_, BV[2], acc[m_][2], 0, 0, 0); \
                acc[m_][3] = __builtin_amdgcn_mfma_f32_16x16x32_bf16(a_, BV[3], acc[m_][3], 0, 0, 0); \
            }                                                               \
        }                                                                   \
    }

__global__ __launch_bounds__(512, 2) void scan_mfma(
    const int*   __restrict__ char_ids,
    const int*   __restrict__ char_lengths,
    const float* __restrict__ char_table,
    const float* __restrict__ bg, const float* __restrict__ bp,
    const uint4* __restrict__ Wpacked,
    const int*   __restrict__ order,
    unsigned short* __restrict__ char_repr)
{
    __shared__ __align__(16) float S[TW * ST];                // 33 KB fp32 state
    __shared__ __align__(16) unsigned short X[64 * 256];      // 32 KB bf16, swizzled
    __shared__ int toksh[TW];
    __shared__ int Lsh[TW];

    const int tid  = threadIdx.x;
    const int lane = tid & 63;
    const int w    = tid >> 6;         // wave 0..7
    const int col  = lane & 15;
    const int q    = lane >> 4;        // 0..3

    if (tid < TW) {
        const int tok = order[blockIdx.x * TW + tid];
        toksh[tid] = tok;
        Lsh[tid]   = char_lengths[tok];
    }

    const int dj = w * 16 + col;
    float biasv[4];
    biasv[0] = bg[dj];
    biasv[1] = bg[128 + dj];
    biasv[2] = bg[256 + dj];
    biasv[3] = bp[dj];

    // pinned kf=0,1 weight fragments (step-invariant, loaded once)
    short8 bpin[4], bpin1[4];
    LOAD_B(bpin, 0);
    LOAD_B(bpin1, 1);

    __syncthreads();

    // init state: S[t][c][d] = char_table[ids[tok[t]][c]][d]
    for (int i = tid; i < TW * SCC * (CD / 4); i += 512) {
        const int t   = i >> 9;
        const int rem = i & 511;
        const int c   = rem >> 5;
        const int d4  = rem & 31;
        const int id  = char_ids[toksh[t] * SCC + c];
        const float4 v = reinterpret_cast<const float4*>(char_table + id * CD)[d4];
        *reinterpret_cast<float4*>(S + t * ST + c * SP + d4 * 4) = v;
    }

    int L[TW];
#pragma unroll
    for (int t = 0; t < TW; ++t) L[t] = Lsh[t];
    const int maxL = max(max(L[0], L[1]), max(L[2], L[3]));

    __syncthreads();

    // init X once: row r=p*4+t = [S[t][p] | S[t][p+1]] bf16,
    // p=15 rows zero-filled. Left/right halves read EXPLICITLY (pad-safe).
    for (int i = tid; i < 64 * 128; i += 512) {
        const int r  = i >> 7;
        const int ku = i & 127;
        const int p  = r >> 2;
        const int t  = r & 3;
        unsigned u = 0u;
        if (p < 15) {
            float2 v;
            if (ku < 64)
                v = *reinterpret_cast<const float2*>(S + t * ST + p * SP + 2 * ku);
            else
                v = *reinterpret_cast<const float2*>(S + t * ST + (p + 1) * SP + 2 * (ku - 64));
            u = f2bf(v.x) | ((unsigned)f2bf(v.y) << 16);
        }
        int baddr = (r << 9) + (ku << 2);
        baddr ^= (r & 7) << 4;
        *reinterpret_cast<unsigned*>(reinterpret_cast<char*>(X) + baddr) = u;
    }
    __syncthreads();

    for (int len = 1; len < maxL; ++len) {
        const int Amax   = maxL - len;
        const int mfrags = (4 * Amax + 15) >> 4;       // <= 4

        f32x4 acc[4][4];   // [m-frag][chunk] -> 64 regs (accumulator class)
#pragma unroll
        for (int m = 0; m < 4; ++m)
#pragma unroll
            for (int c = 0; c < 4; ++c) acc[m][c] = (f32x4){0.f, 0.f, 0.f, 0.f};

        // ---- MFMA phase: depth-2 pipelined B loads, kf=0,1 pinned ----
        short8 bA[4], bB[4];
        LOAD_B(bA, 2);
        MFMA_PHASE(bpin, 0);
        MFMA_PHASE(bpin1, 1);
#pragma unroll 1
        for (int kh = 0; kh < 2; ++kh) {      // kf pairs: (2,3),(4,5)
            LOAD_B(bB, 3 + 2 * kh);
            MFMA_PHASE(bA, 2 + 2 * kh);
            LOAD_B(bA, 4 + 2 * kh);
            MFMA_PHASE(bB, 3 + 2 * kh);
        }
        LOAD_B(bB, 7);
        MFMA_PHASE(bA, 6);
        MFMA_PHASE(bB, 7);

        // ---- combine: lane-local softmax (no max-sub; |g|<~1) + mix ----
#pragma unroll
        for (int m = 0; m < 4; ++m) {
            if (m < mfrags) {
                const int p = m * 4 + q;
#pragma unroll
                for (int i = 0; i < 4; ++i) {
                    const float g0 = acc[m][0][i] + biasv[0];
                    const float g1 = acc[m][1][i] + biasv[1];
                    const float g2 = acc[m][2][i] + biasv[2];
                    const float z  = acc[m][3][i] + biasv[3];
                    const float e0 = __expf(g0);
                    const float e1 = __expf(g1);
                    const float e2 = __expf(g2);
                    const float left  = S[i * ST + p * SP + dj];
                    const float right = S[i * ST + (p + 1) * SP + dj];
                    const float inv = __builtin_amdgcn_rcpf(e0 + e1 + e2);
                    acc[m][0][i] = (e0 * left + e1 * right + e2 * z) * inv;
                }
            }
        }
        __syncthreads();   // all X-reads (MFMA) and S-reads (combine) done

        // ---- write phase: masked fp32 S + bf16 X (left @ p, right @ p-1) ----
#pragma unroll
        for (int m = 0; m < 4; ++m) {
            if (m < mfrags) {
                const int p = m * 4 + q;
#pragma unroll
                for (int i = 0; i < 4; ++i) {
                    const float val = acc[m][0][i];
                    if (p < L[i] - len) S[i * ST + p * SP + dj] = val;
                    const unsigned short bv = f2bf(val);
                    const int rl = m * 16 + q * 4 + i;          // row p*4+i
                    int bl = (rl << 9) + (dj << 1);
                    bl ^= (rl & 7) << 4;
                    *reinterpret_cast<unsigned short*>(
                        reinterpret_cast<char*>(X) + bl) = bv;
                    if (p >= 1) {
                        const int rr = rl - 4;                  // row (p-1)*4+i
                        int br = (rr << 9) + 256 + (dj << 1);
                        br ^= (rr & 7) << 4;
                        *reinterpret_cast<unsigned short*>(
                            reinterpret_cast<char*>(X) + br) = bv;
                    }
                }
            }
        }
        __syncthreads();
    }

    // char representation = S[t][0][:], stored bf16
    for (int i = tid; i < TW * CD; i += 512) {
        const int t = i >> 7, d = i & 127;
        char_repr[toksh[t] * CD + d] = f2bf(S[t * ST + d]);
    }
}

// ---------------------------------------------------------------------------
// Kernel 2: MFMA out-projection. out[t][j] = b_out[j] + emb[t].W_out[j].
// ---------------------------------------------------------------------------
__global__ __launch_bounds__(256) void out_mfma(
    const int*   __restrict__ word_inputs,
    const float* __restrict__ word_table,
    const unsigned short* __restrict__ char_repr,   // bf16 bits
    const uint4* __restrict__ pwout,
    const float* __restrict__ b_out,
    float*       __restrict__ out)
{
    __shared__ __align__(16) unsigned short E[16 * ED];   // 20 KB, swizzled

    const int tg   = blockIdx.x * 16;
    const int tid  = threadIdx.x;
    const int lane = tid & 63;
    const int w    = tid >> 6;         // wave 0..3
    const int col  = lane & 15;
    const int q    = lane >> 4;

    // stage word part: 16 tokens x 512 dims as bf16 pairs
    for (int i = tid; i < 16 * 256; i += 256) {
        const int rt = i >> 8, kp = i & 255;     // dims 2kp, 2kp+1
        const float2 v = *reinterpret_cast<const float2*>(
            word_table + (size_t)word_inputs[tg + rt] * WD + 2 * kp);
        const unsigned u = f2bf(v.x) | ((unsigned)f2bf(v.y) << 16);
        int baddr = rt * 1280 + kp * 4;
        baddr ^= (rt & 7) << 4;
        *reinterpret_cast<unsigned*>(reinterpret_cast<char*>(E) + baddr) = u;
    }
    // stage char part: 16 tokens x 128 dims (already bf16)
    for (int i = tid; i < 16 * 64; i += 256) {
        const int rt = i >> 6, kp = i & 63;      // dims 512+2kp, 512+2kp+1
        const unsigned u = *reinterpret_cast<const unsigned*>(
            char_repr + (tg + rt) * CD + 2 * kp);
        int baddr = rt * 1280 + 1024 + kp * 4;
        baddr ^= (rt & 7) << 4;
        *reinterpret_cast<unsigned*>(reinterpret_cast<char*>(E) + baddr) = u;
    }
    __syncthreads();

    f32x4 acc[16];
#pragma unroll
    for (int nf = 0; nf < 16; ++nf) acc[nf] = (f32x4){0.f, 0.f, 0.f, 0.f};

#pragma unroll 4
    for (int kf = 0; kf < 20; ++kf) {
        // A: token row = col, k0 = kf*32 + q*8
        int ba = col * 1280 + kf * 64 + q * 16;
        ba ^= (col & 7) << 4;
        const short8 a = *reinterpret_cast<const short8*>(
            reinterpret_cast<const char*>(E) + ba);
#pragma unroll
        for (int nf = 0; nf < 16; ++nf) {
            const int nb = w * 16 + nf;
            union { uint4 u; short8 s; } cv;
            cv.u = pwout[(nb * 20 + kf) * 64 + lane];
            acc[nf] = __builtin_amdgcn_mfma_f32_16x16x32_bf16(a, cv.s, acc[nf], 0, 0, 0);
        }
    }

#pragma unroll
    for (int nf = 0; nf < 16; ++nf) {
        const int j = (w * 16 + nf) * 16 + col;
        const float bias = b_out[j];
#pragma unroll
        for (int i = 0; i < 4; ++i) {
            out[(size_t)(tg + q * 4 + i) * OD + j] = acc[nf][i] + bias;
        }
    }
}

// ---------------------------------------------------------------------------

extern "C" void kernel_launch(void* const* d_in, const int* in_sizes, int n_in,
                              void* d_out, int out_size, void* d_ws, size_t ws_size,
                              hipStream_t stream)
{
    const int*   word_inputs  = (const int*)  d_in[0];
    const int*   char_ids     = (const int*)  d_in[1];
    const int*   char_lengths = (const int*)  d_in[2];
    const float* word_table   = (const float*)d_in[3];
    const float* char_table   = (const float*)d_in[4];
    const float* Wg           = (const float*)d_in[5];
    const float* bg           = (const float*)d_in[6];
    const float* Wp           = (const float*)d_in[7];
    const float* bp           = (const float*)d_in[8];
    const float* W_out        = (const float*)d_in[9];
    const float* b_out        = (const float*)d_in[10];

    float* out = (float*)d_out;
    char* ws = (char*)d_ws;
    unsigned short* char_repr = (unsigned short*)ws;                 // 2 MB bf16
    uint4* Wpacked = (uint4*)(ws + 2 * 1024 * 1024);                 // 256 KB
    int*   sortbuf = (int*)(ws + 2 * 1024 * 1024 + 256 * 1024);      // 33 KB
    const int* order = sortbuf + 48;
    uint4* pwout = (uint4*)(ws + 2 * 1024 * 1024 + 256 * 1024 + 64 * 1024); // 1.3 MB

    pack_weights<<<64, 256, 0, stream>>>(Wg, Wp, Wpacked);
    pack_wout<<<320, 256, 0, stream>>>(W_out, pwout);
    sort_zero<<<1, 64, 0, stream>>>(sortbuf);
    sort_hist<<<NTOK / 256, 256, 0, stream>>>(char_lengths, sortbuf);
    sort_prefix<<<1, 64, 0, stream>>>(sortbuf);
    sort_scatter_det<<<16, 256, 0, stream>>>(char_lengths, sortbuf);

    scan_mfma<<<NTOK / TW, 512, 0, stream>>>(char_ids, char_lengths, char_table,
                                             bg, bp, Wpacked, order, char_repr);
    out_mfma<<<NTOK / 16, 256, 0, stream>>>(word_inputs, word_table, char_repr,
                                            pwout, b_out, out);
}

// Round 15
// 270.932 us; speedup vs baseline: 3.9074x; 1.1418x over previous
//
#include <hip/hip_runtime.h>
#include <hip/hip_bf16.h>

#define NTOK 8192
#define SCC  16
#define CD   128
#define WD   512
#define OD   1024
#define ED   640   // WD + CD
#define TW   4     // tokens per scan workgroup
#define SP   132   // padded S row stride (floats)
#define ST   (SCC * SP)

typedef __attribute__((ext_vector_type(8))) short short8;
typedef __attribute__((ext_vector_type(4))) float f32x4;

__device__ __forceinline__ unsigned short f2bf(float f) {
    union { float f; unsigned u; } v; v.f = f;
    unsigned r = v.u + 0x7FFF + ((v.u >> 16) & 1);   // RNE
    return (unsigned short)(r >> 16);
}

// ---------------------------------------------------------------------------
// Deterministic stable counting sort of tokens by length, LONGEST FIRST (LPT).
// ws ints: [0..15]=hist [16..31]=base [32..47]=unused [48..48+NTOK)=order
// ---------------------------------------------------------------------------
__global__ void sort_zero(int* s) { if (threadIdx.x < 48) s[threadIdx.x] = 0; }

__global__ void sort_hist(const int* __restrict__ lengths, int* __restrict__ s) {
    const int i = blockIdx.x * 256 + threadIdx.x;
    if (i < NTOK) atomicAdd(&s[lengths[i] - 1], 1);
}

__global__ void sort_prefix(int* s) {
    if (threadIdx.x == 0) {
        int acc = 0;
        for (int b = 15; b >= 0; --b) { s[16 + b] = acc; acc += s[b]; }  // LPT
    }
}

__global__ __launch_bounds__(256) void sort_scatter_det(
    const int* __restrict__ lengths, int* __restrict__ s)
{
    __shared__ int wsum[4];
    __shared__ int running;
    const int b   = blockIdx.x;
    const int tid = threadIdx.x;
    if (tid == 0) running = s[16 + b];
    __syncthreads();
    for (int c0 = 0; c0 < NTOK; c0 += 256) {
        const int i = c0 + tid;
        const bool f = (lengths[i] - 1 == b);
        const unsigned long long m = __ballot(f);
        const int wv = tid >> 6;
        if ((tid & 63) == 0) wsum[wv] = __popcll(m);
        __syncthreads();
        int excl = 0;
#pragma unroll
        for (int k = 0; k < 4; ++k) if (k < wv) excl += wsum[k];
        const int lanerank = __popcll(m & ((1ull << (tid & 63)) - 1ull));
        if (f) s[48 + running + excl + lanerank] = i;
        const int tot = wsum[0] + wsum[1] + wsum[2] + wsum[3];
        __syncthreads();
        if (tid == 0) running += tot;
        __syncthreads();
    }
}

// ---------------------------------------------------------------------------
// Kernel 0a: pack Wg(384x256)+Wp(128x256) fp32 -> bf16 B-fragment layout.
// index: (w*32 + c*8 + kf)*64 + lane, entry = uint4 (8 bf16 along k).
// ---------------------------------------------------------------------------
__global__ __launch_bounds__(256) void pack_weights(
    const float* __restrict__ Wg, const float* __restrict__ Wp,
    uint4* __restrict__ packed)
{
    const int gid  = blockIdx.x * 256 + threadIdx.x;  // 0..16383
    const int lane = gid & 63;
    const int kf   = (gid >> 6) & 7;
    const int c    = (gid >> 9) & 3;
    const int w    = (gid >> 11) & 7;
    const int n    = c * 128 + w * 16 + (lane & 15);
    const int k0   = kf * 32 + (lane >> 4) * 8;
    const float* src = (n < 384) ? (Wg + n * 256 + k0) : (Wp + (n - 384) * 256 + k0);
    uint4 o;
    o.x = f2bf(src[0]) | ((unsigned)f2bf(src[1]) << 16);
    o.y = f2bf(src[2]) | ((unsigned)f2bf(src[3]) << 16);
    o.z = f2bf(src[4]) | ((unsigned)f2bf(src[5]) << 16);
    o.w = f2bf(src[6]) | ((unsigned)f2bf(src[7]) << 16);
    packed[gid] = o;
}

// ---------------------------------------------------------------------------
// Kernel 0b: pack W_out (1024x640) fp32 -> bf16 B-fragments.
// ---------------------------------------------------------------------------
__global__ __launch_bounds__(256) void pack_wout(
    const float* __restrict__ W_out, uint4* __restrict__ packed)
{
    const int gid  = blockIdx.x * 256 + threadIdx.x;  // 0..81919
    const int lane = gid & 63;
    const int kf   = (gid >> 6) % 20;
    const int nb   = (gid >> 6) / 20;
    const int n    = nb * 16 + (lane & 15);
    const int k0   = kf * 32 + (lane >> 4) * 8;
    const float* src = W_out + (size_t)n * ED + k0;
    uint4 o;
    o.x = f2bf(src[0]) | ((unsigned)f2bf(src[1]) << 16);
    o.y = f2bf(src[2]) | ((unsigned)f2bf(src[3]) << 16);
    o.z = f2bf(src[4]) | ((unsigned)f2bf(src[5]) << 16);
    o.w = f2bf(src[6]) | ((unsigned)f2bf(src[7]) << 16);
    packed[gid] = o;
}

// ---------------------------------------------------------------------------
// Kernel 1: MFMA gated pyramid scan. TW=4 LPT-sorted tokens/WG, 8 waves.
// R14 found 1 WG/CU (reg-limited, 188 unified/wave) -> 93 KB LDS free.
// This round: (a) kf 0,1 pinned in regs; kf 2,3,4 stashed in LDS (96 KB,
// filled once); only kf 5-7 stream from L2 per step (traffic 2.9->1.46 GB).
// (b) X stores LEFT only: right(p) = left(p+1) read at row r+4. 256B rows,
// XOR swizzle (r&15)<<4 -> conflict-free A-reads, <=2-way writes, half the
// X write ops. (c) 2-exp softmax (divide through by e2).
// X rows 0..67: r = p*4+t for p<15 live; r 60..67 zero (dead p=15/p=16).
// ---------------------------------------------------------------------------
#define LOAD_B(DST, KF)                                                     \
    {                                                                       \
        const uint4* wp_ = Wpacked + (w * 32 + (KF)) * 64 + lane;           \
        union { uint4 u; short8 s; } cv0, cv1, cv2, cv3;                    \
        cv0.u = wp_[0];    DST[0] = cv0.s;                                  \
        cv1.u = wp_[512];  DST[1] = cv1.s;                                  \
        cv2.u = wp_[1024]; DST[2] = cv2.s;                                  \
        cv3.u = wp_[1536]; DST[3] = cv3.s;                                  \
    }

// stash slot for kf = 2+KFI of this wave: SW[((w*3+KFI)*4 + c)*64 + lane]
#define LOAD_B_LDS(DST, KFI)                                                \
    {                                                                       \
        const uint4* sp_ = SW + ((w * 3 + (KFI)) * 4) * 64 + lane;          \
        union { uint4 u; short8 s; } d0, d1, d2, d3;                        \
        d0.u = sp_[0];   DST[0] = d0.s;                                     \
        d1.u = sp_[64];  DST[1] = d1.s;                                     \
        d2.u = sp_[128]; DST[2] = d2.s;                                     \
        d3.u = sp_[192]; DST[3] = d3.s;                                     \
    }

#define MFMA_PHASE(BV, KF)                                                  \
    {                                                                       \
        _Pragma("unroll")                                                   \
        for (int m_ = 0; m_ < 4; ++m_) {                                    \
            if (m_ < mfrags) {                                              \
                const int r_ = m_ * 16 + col + (((KF) >= 4) ? 4 : 0);       \
                int ba_ = (r_ << 8) + (((KF) & 3) << 6) + (q << 4);         \
                ba_ ^= (r_ & 15) << 4;                                      \
                const short8 a_ = *reinterpret_cast<const short8*>(         \
                    reinterpret_cast<const char*>(X) + ba_);                \
                acc[m_][0] = __builtin_amdgcn_mfma_f32_16x16x32_bf16(a_, BV[0], acc[m_][0], 0, 0, 0); \
                acc[m_][1] = __builtin_amdgcn_mfma_f32_16x16x32_bf16(a_, BV[1], acc[m_][1], 0, 0, 0); \
                acc[m_][2] = __builtin_amdgcn_mfma_f32_16x16x32_bf16(a_, BV[2], acc[m_][2], 0, 0, 0); \
                acc[m_][3] = __builtin_amdgcn_mfma_f32_16x16x32_bf16(a_, BV[3], acc[m_][3], 0, 0, 0); \
            }                                                               \
        }                                                                   \
    }

__global__ __launch_bounds__(512, 2) void scan_mfma(
    const int*   __restrict__ char_ids,
    const int*   __restrict__ char_lengths,
    const float* __restrict__ char_table,
    const float* __restrict__ bg, const float* __restrict__ bp,
    const uint4* __restrict__ Wpacked,
    const int*   __restrict__ order,
    unsigned short* __restrict__ char_repr)
{
    __shared__ __align__(16) float S[TW * ST];                // 33 KB fp32 state
    __shared__ __align__(16) unsigned short X[68 * 128];      // 17 KB bf16 (left only)
    __shared__ __align__(16) uint4 SW[8 * 3 * 4 * 64];        // 96 KB kf=2,3,4 stash
    __shared__ int toksh[TW];
    __shared__ int Lsh[TW];

    const int tid  = threadIdx.x;
    const int lane = tid & 63;
    const int w    = tid >> 6;         // wave 0..7
    const int col  = lane & 15;
    const int q    = lane >> 4;        // 0..3

    if (tid < TW) {
        const int tok = order[blockIdx.x * TW + tid];
        toksh[tid] = tok;
        Lsh[tid]   = char_lengths[tok];
    }

    const int dj = w * 16 + col;
    const float b02 = bg[dj] - bg[256 + dj];
    const float b12 = bg[128 + dj] - bg[256 + dj];
    const float bz  = bp[dj];

    // pinned kf=0,1 weight fragments (step-invariant, loaded once)
    short8 bpin0[4], bpin1[4];
    LOAD_B(bpin0, 0);
    LOAD_B(bpin1, 1);

    // fill the LDS stash: this wave's kf=2,3,4 slices (no cross-wave sharing)
#pragma unroll
    for (int kfi = 0; kfi < 3; ++kfi)
#pragma unroll
        for (int c = 0; c < 4; ++c)
            SW[((w * 3 + kfi) * 4 + c) * 64 + lane] =
                Wpacked[(w * 32 + c * 8 + (2 + kfi)) * 64 + lane];

    __syncthreads();

    // init state: S[t][c][d] = char_table[ids[tok[t]][c]][d]
    for (int i = tid; i < TW * SCC * (CD / 4); i += 512) {
        const int t   = i >> 9;
        const int rem = i & 511;
        const int c   = rem >> 5;
        const int d4  = rem & 31;
        const int id  = char_ids[toksh[t] * SCC + c];
        const float4 v = reinterpret_cast<const float4*>(char_table + id * CD)[d4];
        *reinterpret_cast<float4*>(S + t * ST + c * SP + d4 * 4) = v;
    }

    int L[TW];
#pragma unroll
    for (int t = 0; t < TW; ++t) L[t] = Lsh[t];
    const int maxL = max(max(L[0], L[1]), max(L[2], L[3]));

    __syncthreads();

    // init X once: row r=p*4+t holds bf16 of S[t][p][0..127]; r in [60,68) zero
    for (int i = tid; i < 68 * 64; i += 512) {
        const int r  = i >> 6;
        const int ku = i & 63;
        unsigned u = 0u;
        if (r < 60) {
            const int p = r >> 2, t = r & 3;
            const float2 v = *reinterpret_cast<const float2*>(S + t * ST + p * SP + 2 * ku);
            u = f2bf(v.x) | ((unsigned)f2bf(v.y) << 16);
        }
        int ba = (r << 8) + (ku << 2);
        ba ^= (r & 15) << 4;
        *reinterpret_cast<unsigned*>(reinterpret_cast<char*>(X) + ba) = u;
    }
    __syncthreads();

    for (int len = 1; len < maxL; ++len) {
        const int Amax   = maxL - len;
        const int mfrags = (4 * Amax + 15) >> 4;       // <= 4

        f32x4 acc[4][4];   // [m-frag][chunk] -> 64 regs (accumulator class)
#pragma unroll
        for (int m = 0; m < 4; ++m)
#pragma unroll
            for (int c = 0; c < 4; ++c) acc[m][c] = (f32x4){0.f, 0.f, 0.f, 0.f};

        // ---- MFMA phase: kf0,1 pinned; kf2-4 from LDS stash; kf5-7 L2 ----
        short8 bA[4], bB[4], bL[4];
        LOAD_B(bA, 5);
        LOAD_B(bB, 6);
        MFMA_PHASE(bpin0, 0);
        LOAD_B_LDS(bL, 0);
        MFMA_PHASE(bpin1, 1);
        MFMA_PHASE(bL, 2);
        LOAD_B_LDS(bL, 1);
        MFMA_PHASE(bL, 3);
        LOAD_B_LDS(bL, 2);
        MFMA_PHASE(bL, 4);
        MFMA_PHASE(bA, 5);
        LOAD_B(bA, 7);
        MFMA_PHASE(bB, 6);
        MFMA_PHASE(bA, 7);

        // ---- combine: 2-exp softmax (/(e2)) + convex mix. t=i, p=m*4+q ----
#pragma unroll
        for (int m = 0; m < 4; ++m) {
            if (m < mfrags) {
                const int p = m * 4 + q;
#pragma unroll
                for (int i = 0; i < 4; ++i) {
                    const float a0  = acc[m][0][i];
                    const float a1  = acc[m][1][i];
                    const float a2v = acc[m][2][i];
                    const float z   = acc[m][3][i] + bz;
                    const float E0  = __expf(a0 - a2v + b02);
                    const float E1  = __expf(a1 - a2v + b12);
                    const float left  = S[i * ST + p * SP + dj];
                    const float right = S[i * ST + (p + 1) * SP + dj];
                    const float inv = __builtin_amdgcn_rcpf(E0 + E1 + 1.0f);
                    acc[m][0][i] = (E0 * left + E1 * right + z) * inv;
                }
            }
        }
        __syncthreads();   // all X-reads (MFMA) and S-reads (combine) done

        // ---- write phase: masked fp32 S + single bf16 X write (left @ p) ----
#pragma unroll
        for (int m = 0; m < 4; ++m) {
            if (m < mfrags) {
                const int p = m * 4 + q;
#pragma unroll
                for (int i = 0; i < 4; ++i) {
                    const float val = acc[m][0][i];
                    if (p < L[i] - len) S[i * ST + p * SP + dj] = val;
                    const unsigned short bv = f2bf(val);
                    const int rl = m * 16 + q * 4 + i;          // row p*4+i
                    int bl = (rl << 8) + (dj << 1);
                    bl ^= (rl & 15) << 4;
                    *reinterpret_cast<unsigned short*>(
                        reinterpret_cast<char*>(X) + bl) = bv;
                }
            }
        }
        __syncthreads();
    }

    // char representation = S[t][0][:], stored bf16
    for (int i = tid; i < TW * CD; i += 512) {
        const int t = i >> 7, d = i & 127;
        char_repr[toksh[t] * CD + d] = f2bf(S[t * ST + d]);
    }
}

// ---------------------------------------------------------------------------
// Kernel 2: MFMA out-projection. out[t][j] = b_out[j] + emb[t].W_out[j].
// ---------------------------------------------------------------------------
__global__ __launch_bounds__(256) void out_mfma(
    const int*   __restrict__ word_inputs,
    const float* __restrict__ word_table,
    const unsigned short* __restrict__ char_repr,   // bf16 bits
    const uint4* __restrict__ pwout,
    const float* __restrict__ b_out,
    float*       __restrict__ out)
{
    __shared__ __align__(16) unsigned short E[16 * ED];   // 20 KB, swizzled

    const int tg   = blockIdx.x * 16;
    const int tid  = threadIdx.x;
    const int lane = tid & 63;
    const int w    = tid >> 6;         // wave 0..3
    const int col  = lane & 15;
    const int q    = lane >> 4;

    for (int i = tid; i < 16 * 256; i += 256) {
        const int rt = i >> 8, kp = i & 255;
        const float2 v = *reinterpret_cast<const float2*>(
            word_table + (size_t)word_inputs[tg + rt] * WD + 2 * kp);
        const unsigned u = f2bf(v.x) | ((unsigned)f2bf(v.y) << 16);
        int baddr = rt * 1280 + kp * 4;
        baddr ^= (rt & 7) << 4;
        *reinterpret_cast<unsigned*>(reinterpret_cast<char*>(E) + baddr) = u;
    }
    for (int i = tid; i < 16 * 64; i += 256) {
        const int rt = i >> 6, kp = i & 63;
        const unsigned u = *reinterpret_cast<const unsigned*>(
            char_repr + (tg + rt) * CD + 2 * kp);
        int baddr = rt * 1280 + 1024 + kp * 4;
        baddr ^= (rt & 7) << 4;
        *reinterpret_cast<unsigned*>(reinterpret_cast<char*>(E) + baddr) = u;
    }
    __syncthreads();

    f32x4 acc[16];
#pragma unroll
    for (int nf = 0; nf < 16; ++nf) acc[nf] = (f32x4){0.f, 0.f, 0.f, 0.f};

#pragma unroll 4
    for (int kf = 0; kf < 20; ++kf) {
        int ba = col * 1280 + kf * 64 + q * 16;
        ba ^= (col & 7) << 4;
        const short8 a = *reinterpret_cast<const short8*>(
            reinterpret_cast<const char*>(E) + ba);
#pragma unroll
        for (int nf = 0; nf < 16; ++nf) {
            const int nb = w * 16 + nf;
            union { uint4 u; short8 s; } cv;
            cv.u = pwout[(nb * 20 + kf) * 64 + lane];
            acc[nf] = __builtin_amdgcn_mfma_f32_16x16x32_bf16(a, cv.s, acc[nf], 0, 0, 0);
        }
    }

#pragma unroll
    for (int nf = 0; nf < 16; ++nf) {
        const int j = (w * 16 + nf) * 16 + col;
        const float bias = b_out[j];
#pragma unroll
        for (int i = 0; i < 4; ++i) {
            out[(size_t)(tg + q * 4 + i) * OD + j] = acc[nf][i] + bias;
        }
    }
}

// ---------------------------------------------------------------------------

extern "C" void kernel_launch(void* const* d_in, const int* in_sizes, int n_in,
                              void* d_out, int out_size, void* d_ws, size_t ws_size,
                              hipStream_t stream)
{
    const int*   word_inputs  = (const int*)  d_in[0];
    const int*   char_ids     = (const int*)  d_in[1];
    const int*   char_lengths = (const int*)  d_in[2];
    const float* word_table   = (const float*)d_in[3];
    const float* char_table   = (const float*)d_in[4];
    const float* Wg           = (const float*)d_in[5];
    const float* bg           = (const float*)d_in[6];
    const float* Wp           = (const float*)d_in[7];
    const float* bp           = (const float*)d_in[8];
    const float* W_out        = (const float*)d_in[9];
    const float* b_out        = (const float*)d_in[10];

    float* out = (float*)d_out;
    char* ws = (char*)d_ws;
    unsigned short* char_repr = (unsigned short*)ws;                 // 2 MB bf16
    uint4* Wpacked = (uint4*)(ws + 2 * 1024 * 1024);                 // 256 KB
    int*   sortbuf = (int*)(ws + 2 * 1024 * 1024 + 256 * 1024);      // 33 KB
    const int* order = sortbuf + 48;
    uint4* pwout = (uint4*)(ws + 2 * 1024 * 1024 + 256 * 1024 + 64 * 1024); // 1.3 MB

    pack_weights<<<64, 256, 0, stream>>>(Wg, Wp, Wpacked);
    pack_wout<<<320, 256, 0, stream>>>(W_out, pwout);
    sort_zero<<<1, 64, 0, stream>>>(sortbuf);
    sort_hist<<<NTOK / 256, 256, 0, stream>>>(char_lengths, sortbuf);
    sort_prefix<<<1, 64, 0, stream>>>(sortbuf);
    sort_scatter_det<<<16, 256, 0, stream>>>(char_lengths, sortbuf);

    scan_mfma<<<NTOK / TW, 512, 0, stream>>>(char_ids, char_lengths, char_table,
                                             bg, bp, Wpacked, order, char_repr);
    out_mfma<<<NTOK / 16, 256, 0, stream>>>(word_inputs, word_table, char_repr,
                                            pwout, b_out, out);
}

// Round 16
// 267.843 us; speedup vs baseline: 3.9525x; 1.0115x over previous
//
#include <hip/hip_runtime.h>
#include <hip/hip_bf16.h>

#define NTOK 8192
#define SCC  16
#define CD   128
#define WD   512
#define OD   1024
#define ED   640   // WD + CD
#define TW   4     // tokens per scan workgroup

typedef __attribute__((ext_vector_type(8))) short short8;
typedef __attribute__((ext_vector_type(4))) float f32x4;

__device__ __forceinline__ unsigned short f2bf(float f) {
    union { float f; unsigned u; } v; v.f = f;
    unsigned r = v.u + 0x7FFF + ((v.u >> 16) & 1);   // RNE
    return (unsigned short)(r >> 16);
}

// ---------------------------------------------------------------------------
// Deterministic stable counting sort of tokens by length, LONGEST FIRST (LPT).
// ws ints: [0..15]=hist [16..31]=base [32..47]=unused [48..48+NTOK)=order
// ---------------------------------------------------------------------------
__global__ void sort_zero(int* s) { if (threadIdx.x < 48) s[threadIdx.x] = 0; }

__global__ void sort_hist(const int* __restrict__ lengths, int* __restrict__ s) {
    const int i = blockIdx.x * 256 + threadIdx.x;
    if (i < NTOK) atomicAdd(&s[lengths[i] - 1], 1);
}

__global__ void sort_prefix(int* s) {
    if (threadIdx.x == 0) {
        int acc = 0;
        for (int b = 15; b >= 0; --b) { s[16 + b] = acc; acc += s[b]; }  // LPT
    }
}

__global__ __launch_bounds__(256) void sort_scatter_det(
    const int* __restrict__ lengths, int* __restrict__ s)
{
    __shared__ int wsum[4];
    __shared__ int running;
    const int b   = blockIdx.x;
    const int tid = threadIdx.x;
    if (tid == 0) running = s[16 + b];
    __syncthreads();
    for (int c0 = 0; c0 < NTOK; c0 += 256) {
        const int i = c0 + tid;
        const bool f = (lengths[i] - 1 == b);
        const unsigned long long m = __ballot(f);
        const int wv = tid >> 6;
        if ((tid & 63) == 0) wsum[wv] = __popcll(m);
        __syncthreads();
        int excl = 0;
#pragma unroll
        for (int k = 0; k < 4; ++k) if (k < wv) excl += wsum[k];
        const int lanerank = __popcll(m & ((1ull << (tid & 63)) - 1ull));
        if (f) s[48 + running + excl + lanerank] = i;
        const int tot = wsum[0] + wsum[1] + wsum[2] + wsum[3];
        __syncthreads();
        if (tid == 0) running += tot;
        __syncthreads();
    }
}

// ---------------------------------------------------------------------------
// Kernel 0a: pack Wg(384x256)+Wp(128x256) fp32 -> bf16 B-fragment layout.
// index: (w*32 + c*8 + kf)*64 + lane, entry = uint4 (8 bf16 along k).
// ---------------------------------------------------------------------------
__global__ __launch_bounds__(256) void pack_weights(
    const float* __restrict__ Wg, const float* __restrict__ Wp,
    uint4* __restrict__ packed)
{
    const int gid  = blockIdx.x * 256 + threadIdx.x;  // 0..16383
    const int lane = gid & 63;
    const int kf   = (gid >> 6) & 7;
    const int c    = (gid >> 9) & 3;
    const int w    = (gid >> 11) & 7;
    const int n    = c * 128 + w * 16 + (lane & 15);
    const int k0   = kf * 32 + (lane >> 4) * 8;
    const float* src = (n < 384) ? (Wg + n * 256 + k0) : (Wp + (n - 384) * 256 + k0);
    uint4 o;
    o.x = f2bf(src[0]) | ((unsigned)f2bf(src[1]) << 16);
    o.y = f2bf(src[2]) | ((unsigned)f2bf(src[3]) << 16);
    o.z = f2bf(src[4]) | ((unsigned)f2bf(src[5]) << 16);
    o.w = f2bf(src[6]) | ((unsigned)f2bf(src[7]) << 16);
    packed[gid] = o;
}

// ---------------------------------------------------------------------------
// Kernel 0b: pack W_out (1024x640) fp32 -> bf16 B-fragments.
// ---------------------------------------------------------------------------
__global__ __launch_bounds__(256) void pack_wout(
    const float* __restrict__ W_out, uint4* __restrict__ packed)
{
    const int gid  = blockIdx.x * 256 + threadIdx.x;  // 0..81919
    const int lane = gid & 63;
    const int kf   = (gid >> 6) % 20;
    const int nb   = (gid >> 6) / 20;
    const int n    = nb * 16 + (lane & 15);
    const int k0   = kf * 32 + (lane >> 4) * 8;
    const float* src = W_out + (size_t)n * ED + k0;
    uint4 o;
    o.x = f2bf(src[0]) | ((unsigned)f2bf(src[1]) << 16);
    o.y = f2bf(src[2]) | ((unsigned)f2bf(src[3]) << 16);
    o.z = f2bf(src[4]) | ((unsigned)f2bf(src[5]) << 16);
    o.w = f2bf(src[6]) | ((unsigned)f2bf(src[7]) << 16);
    packed[gid] = o;
}

// ---------------------------------------------------------------------------
// Kernel 1: MFMA gated pyramid scan. TW=4 LPT-sorted tokens/WG, 8 waves.
// R16: carry state lives in REGISTERS (stv[4][4]), S deleted. Element (m,i)
// = (token i, pos p=m*4+q) in all phases, so: left = own stv; right =
// stv(p+1) = shfl(lane+16) for q<3 else shifted[m+1] (wraps to q'=0).
// stv frozen by mask (p < L-len) — X rewritten with frozen values, so X
// always equals the reference's masked layer (also fixes the R15 p=15
// zero-init bug: stv init includes p=15 = char_table row).
// Weights: kf0,1 pinned in regs; kf2-4 in LDS stash; kf5-7 stream from L2.
// At 1 WG/CU (2 waves/SIMD) unified budget is 256/wave: arch ~140 + acc 64 ok.
// ---------------------------------------------------------------------------
#define LOAD_B(DST, KF)                                                     \
    {                                                                       \
        const uint4* wp_ = Wpacked + (w * 32 + (KF)) * 64 + lane;           \
        union { uint4 u; short8 s; } cv0, cv1, cv2, cv3;                    \
        cv0.u = wp_[0];    DST[0] = cv0.s;                                  \
        cv1.u = wp_[512];  DST[1] = cv1.s;                                  \
        cv2.u = wp_[1024]; DST[2] = cv2.s;                                  \
        cv3.u = wp_[1536]; DST[3] = cv3.s;                                  \
    }

#define LOAD_B_LDS(DST, KFI)                                                \
    {                                                                       \
        const uint4* sp_ = SW + ((w * 3 + (KFI)) * 4) * 64 + lane;          \
        union { uint4 u; short8 s; } d0, d1, d2, d3;                        \
        d0.u = sp_[0];   DST[0] = d0.s;                                     \
        d1.u = sp_[64];  DST[1] = d1.s;                                     \
        d2.u = sp_[128]; DST[2] = d2.s;                                     \
        d3.u = sp_[192]; DST[3] = d3.s;                                     \
    }

#define MFMA_PHASE(BV, KF)                                                  \
    {                                                                       \
        _Pragma("unroll")                                                   \
        for (int m_ = 0; m_ < 4; ++m_) {                                    \
            if (m_ < mfrags) {                                              \
                const int r_ = m_ * 16 + col + (((KF) >= 4) ? 4 : 0);       \
                int ba_ = (r_ << 8) + (((KF) & 3) << 6) + (q << 4);         \
                ba_ ^= (r_ & 15) << 4;                                      \
                const short8 a_ = *reinterpret_cast<const short8*>(         \
                    reinterpret_cast<const char*>(X) + ba_);                \
                acc[m_][0] = __builtin_amdgcn_mfma_f32_16x16x32_bf16(a_, BV[0], acc[m_][0], 0, 0, 0); \
                acc[m_][1] = __builtin_amdgcn_mfma_f32_16x16x32_bf16(a_, BV[1], acc[m_][1], 0, 0, 0); \
                acc[m_][2] = __builtin_amdgcn_mfma_f32_16x16x32_bf16(a_, BV[2], acc[m_][2], 0, 0, 0); \
                acc[m_][3] = __builtin_amdgcn_mfma_f32_16x16x32_bf16(a_, BV[3], acc[m_][3], 0, 0, 0); \
            }                                                               \
        }                                                                   \
    }

__global__ __launch_bounds__(512, 2) void scan_mfma(
    const int*   __restrict__ char_ids,
    const int*   __restrict__ char_lengths,
    const float* __restrict__ char_table,
    const float* __restrict__ bg, const float* __restrict__ bp,
    const uint4* __restrict__ Wpacked,
    const int*   __restrict__ order,
    unsigned short* __restrict__ char_repr)
{
    __shared__ __align__(16) unsigned short X[68 * 128];      // 17 KB bf16 state
    __shared__ __align__(16) uint4 SW[8 * 3 * 4 * 64];        // 96 KB kf=2,3,4 stash
    __shared__ int toksh[TW];
    __shared__ int Lsh[TW];

    const int tid  = threadIdx.x;
    const int lane = tid & 63;
    const int w    = tid >> 6;         // wave 0..7
    const int col  = lane & 15;
    const int q    = lane >> 4;        // 0..3

    if (tid < TW) {
        const int tok = order[blockIdx.x * TW + tid];
        toksh[tid] = tok;
        Lsh[tid]   = char_lengths[tok];
    }

    const int dj = w * 16 + col;
    const float b02 = bg[dj] - bg[256 + dj];
    const float b12 = bg[128 + dj] - bg[256 + dj];
    const float bz  = bp[dj];

    // pinned kf=0,1 weight fragments (step-invariant, loaded once)
    short8 bpin0[4], bpin1[4];
    LOAD_B(bpin0, 0);
    LOAD_B(bpin1, 1);

    // fill the LDS stash: this wave's kf=2,3,4 slices
#pragma unroll
    for (int kfi = 0; kfi < 3; ++kfi)
#pragma unroll
        for (int c = 0; c < 4; ++c)
            SW[((w * 3 + kfi) * 4 + c) * 64 + lane] =
                Wpacked[(w * 32 + c * 8 + (2 + kfi)) * 64 + lane];

    __syncthreads();   // toksh/Lsh + stash ready

    int L[TW];
#pragma unroll
    for (int i = 0; i < TW; ++i) L[i] = Lsh[i];
    const int maxL = max(max(L[0], L[1]), max(L[2], L[3]));

    // init register state: stv[m][i] = char_table[ids[tok[i]][p]][dj], p=m*4+q
    float stv[4][4];
#pragma unroll
    for (int m = 0; m < 4; ++m) {
        const int p = m * 4 + q;
#pragma unroll
        for (int i = 0; i < 4; ++i) {
            const int id = char_ids[toksh[i] * SCC + p];
            stv[m][i] = char_table[id * CD + dj];
        }
    }

    // init X rows 0..63 from stv (includes p=15 true values); zero rows 64..67
#pragma unroll
    for (int m = 0; m < 4; ++m)
#pragma unroll
        for (int i = 0; i < 4; ++i) {
            const int rl = m * 16 + q * 4 + i;
            int bl = (rl << 8) + (dj << 1);
            bl ^= (rl & 15) << 4;
            *reinterpret_cast<unsigned short*>(reinterpret_cast<char*>(X) + bl) =
                f2bf(stv[m][i]);
        }
    for (int i2 = tid; i2 < 4 * 64; i2 += 512) {
        const int r = 64 + (i2 >> 6), ku = i2 & 63;
        int ba = (r << 8) + (ku << 2);
        ba ^= (r & 15) << 4;
        *reinterpret_cast<unsigned*>(reinterpret_cast<char*>(X) + ba) = 0u;
    }
    __syncthreads();

    for (int len = 1; len < maxL; ++len) {
        const int Amax   = maxL - len;
        const int mfrags = (4 * Amax + 15) >> 4;       // <= 4

        f32x4 acc[4][4];   // [m-frag][chunk] -> 64 regs (accumulator class)
#pragma unroll
        for (int m = 0; m < 4; ++m)
#pragma unroll
            for (int c = 0; c < 4; ++c) acc[m][c] = (f32x4){0.f, 0.f, 0.f, 0.f};

        // ---- MFMA phase: kf0,1 pinned; kf2-4 from LDS stash; kf5-7 L2 ----
        short8 bA[4], bB[4], bL[4];
        LOAD_B(bA, 5);
        LOAD_B(bB, 6);
        MFMA_PHASE(bpin0, 0);
        LOAD_B_LDS(bL, 0);
        MFMA_PHASE(bpin1, 1);
        MFMA_PHASE(bL, 2);
        LOAD_B_LDS(bL, 1);
        MFMA_PHASE(bL, 3);
        LOAD_B_LDS(bL, 2);
        MFMA_PHASE(bL, 4);
        MFMA_PHASE(bA, 5);
        LOAD_B(bA, 7);
        MFMA_PHASE(bB, 6);
        MFMA_PHASE(bA, 7);

        // ---- combine: all-register. right(p+1) via shfl(lane+16) ----
        float shifted[5][4];
#pragma unroll
        for (int m = 0; m < 4; ++m)
#pragma unroll
            for (int i = 0; i < 4; ++i)
                shifted[m][i] = __shfl(stv[m][i], (lane + 16) & 63);
#pragma unroll
        for (int i = 0; i < 4; ++i) shifted[4][i] = 0.f;

#pragma unroll
        for (int m = 0; m < 4; ++m) {
            if (m < mfrags) {
                const int p = m * 4 + q;
#pragma unroll
                for (int i = 0; i < 4; ++i) {
                    const float a0  = acc[m][0][i];
                    const float a1  = acc[m][1][i];
                    const float a2v = acc[m][2][i];
                    const float z   = acc[m][3][i] + bz;
                    const float E0  = __expf(a0 - a2v + b02);
                    const float E1  = __expf(a1 - a2v + b12);
                    const float left  = stv[m][i];
                    const float right = (q < 3) ? shifted[m][i] : shifted[m + 1][i];
                    const float inv = __builtin_amdgcn_rcpf(E0 + E1 + 1.0f);
                    const float nv  = (E0 * left + E1 * right + z) * inv;
                    stv[m][i] = (p < L[i] - len) ? nv : stv[m][i];
                }
            }
        }
        __syncthreads();   // all MFMA X-reads done before X writes

        // ---- write phase: X <- bf16(stv) (masked layer, frozen kept) ----
#pragma unroll
        for (int m = 0; m < 4; ++m) {
            if (m < mfrags) {
#pragma unroll
                for (int i = 0; i < 4; ++i) {
                    const int rl = m * 16 + q * 4 + i;
                    int bl = (rl << 8) + (dj << 1);
                    bl ^= (rl & 15) << 4;
                    *reinterpret_cast<unsigned short*>(
                        reinterpret_cast<char*>(X) + bl) = f2bf(stv[m][i]);
                }
            }
        }
        __syncthreads();
    }

    // char representation = state at p=0 (held by q==0 lanes), stored bf16
    if (q == 0) {
#pragma unroll
        for (int i = 0; i < 4; ++i)
            char_repr[toksh[i] * CD + dj] = f2bf(stv[0][i]);
    }
}

// ---------------------------------------------------------------------------
// Kernel 2: MFMA out-projection, 32 tokens/WG, 8 waves.
// Wave w owns feature blocks nb = w*8 .. w*8+7 (128 outputs); acc[2][8]=64.
// W_out L2 traffic halved vs 16-token version (335 MB total).
// ---------------------------------------------------------------------------
#define TPB2 32

__global__ __launch_bounds__(512) void out_mfma(
    const int*   __restrict__ word_inputs,
    const float* __restrict__ word_table,
    const unsigned short* __restrict__ char_repr,   // bf16 bits
    const uint4* __restrict__ pwout,
    const float* __restrict__ b_out,
    float*       __restrict__ out)
{
    __shared__ __align__(16) unsigned short E[TPB2 * ED];   // 40 KB, swizzled

    const int tg   = blockIdx.x * TPB2;
    const int tid  = threadIdx.x;
    const int lane = tid & 63;
    const int w    = tid >> 6;         // wave 0..7
    const int col  = lane & 15;
    const int q    = lane >> 4;

    // stage word part: 32 tokens x 512 dims as bf16 pairs
    for (int i = tid; i < TPB2 * 256; i += 512) {
        const int rt = i >> 8, kp = i & 255;
        const float2 v = *reinterpret_cast<const float2*>(
            word_table + (size_t)word_inputs[tg + rt] * WD + 2 * kp);
        const unsigned u = f2bf(v.x) | ((unsigned)f2bf(v.y) << 16);
        int baddr = rt * 1280 + kp * 4;
        baddr ^= (rt & 7) << 4;
        *reinterpret_cast<unsigned*>(reinterpret_cast<char*>(E) + baddr) = u;
    }
    // stage char part: 32 tokens x 128 dims (already bf16)
    for (int i = tid; i < TPB2 * 64; i += 512) {
        const int rt = i >> 6, kp = i & 63;
        const unsigned u = *reinterpret_cast<const unsigned*>(
            char_repr + (tg + rt) * CD + 2 * kp);
        int baddr = rt * 1280 + 1024 + kp * 4;
        baddr ^= (rt & 7) << 4;
        *reinterpret_cast<unsigned*>(reinterpret_cast<char*>(E) + baddr) = u;
    }
    __syncthreads();

    f32x4 acc[2][8];
#pragma unroll
    for (int mm = 0; mm < 2; ++mm)
#pragma unroll
        for (int nf = 0; nf < 8; ++nf) acc[mm][nf] = (f32x4){0.f, 0.f, 0.f, 0.f};

#pragma unroll 4
    for (int kf = 0; kf < 20; ++kf) {
        short8 a[2];
#pragma unroll
        for (int mm = 0; mm < 2; ++mm) {
            const int row = mm * 16 + col;
            int ba = row * 1280 + kf * 64 + q * 16;
            ba ^= (row & 7) << 4;
            a[mm] = *reinterpret_cast<const short8*>(
                reinterpret_cast<const char*>(E) + ba);
        }
#pragma unroll
        for (int nf = 0; nf < 8; ++nf) {
            const int nb = w * 8 + nf;
            union { uint4 u; short8 s; } cv;
            cv.u = pwout[(nb * 20 + kf) * 64 + lane];
            acc[0][nf] = __builtin_amdgcn_mfma_f32_16x16x32_bf16(a[0], cv.s, acc[0][nf], 0, 0, 0);
            acc[1][nf] = __builtin_amdgcn_mfma_f32_16x16x32_bf16(a[1], cv.s, acc[1][nf], 0, 0, 0);
        }
    }

#pragma unroll
    for (int nf = 0; nf < 8; ++nf) {
        const int j = (w * 8 + nf) * 16 + col;
        const float bias = b_out[j];
#pragma unroll
        for (int mm = 0; mm < 2; ++mm)
#pragma unroll
            for (int i = 0; i < 4; ++i) {
                out[(size_t)(tg + mm * 16 + q * 4 + i) * OD + j] = acc[mm][nf][i] + bias;
            }
    }
}

// ---------------------------------------------------------------------------

extern "C" void kernel_launch(void* const* d_in, const int* in_sizes, int n_in,
                              void* d_out, int out_size, void* d_ws, size_t ws_size,
                              hipStream_t stream)
{
    const int*   word_inputs  = (const int*)  d_in[0];
    const int*   char_ids     = (const int*)  d_in[1];
    const int*   char_lengths = (const int*)  d_in[2];
    const float* word_table   = (const float*)d_in[3];
    const float* char_table   = (const float*)d_in[4];
    const float* Wg           = (const float*)d_in[5];
    const float* bg           = (const float*)d_in[6];
    const float* Wp           = (const float*)d_in[7];
    const float* bp           = (const float*)d_in[8];
    const float* W_out        = (const float*)d_in[9];
    const float* b_out        = (const float*)d_in[10];

    float* out = (float*)d_out;
    char* ws = (char*)d_ws;
    unsigned short* char_repr = (unsigned short*)ws;                 // 2 MB bf16
    uint4* Wpacked = (uint4*)(ws + 2 * 1024 * 1024);                 // 256 KB
    int*   sortbuf = (int*)(ws + 2 * 1024 * 1024 + 256 * 1024);      // 33 KB
    const int* order = sortbuf + 48;
    uint4* pwout = (uint4*)(ws + 2 * 1024 * 1024 + 256 * 1024 + 64 * 1024); // 1.3 MB

    pack_weights<<<64, 256, 0, stream>>>(Wg, Wp, Wpacked);
    pack_wout<<<320, 256, 0, stream>>>(W_out, pwout);
    sort_zero<<<1, 64, 0, stream>>>(sortbuf);
    sort_hist<<<NTOK / 256, 256, 0, stream>>>(char_lengths, sortbuf);
    sort_prefix<<<1, 64, 0, stream>>>(sortbuf);
    sort_scatter_det<<<16, 256, 0, stream>>>(char_lengths, sortbuf);

    scan_mfma<<<NTOK / TW, 512, 0, stream>>>(char_ids, char_lengths, char_table,
                                             bg, bp, Wpacked, order, char_repr);
    out_mfma<<<NTOK / TPB2, 512, 0, stream>>>(word_inputs, word_table, char_repr,
                                              pwout, b_out, out);
}